// Round 1
// baseline (5450.952 us; speedup 1.0000x reference)
//
#include <hip/hip_runtime.h>
#include <math.h>

// ---------------------------------------------------------------------------
// AttModel: 3 stride-2 convs -> 4 anchor convs -> gated-attention MLP ->
// rank/cluster -> weighted segment reduce -> cluster softmax head.
// Round 0: straight fp32, register-blocked direct convs (OCB=8/thread),
// deterministic tree reductions. Anchor convs dominate (63.5 of 107 GFLOP).
// ---------------------------------------------------------------------------

#define NTOT 15376   // 3721 + 3969 + 3843 + 3843 anchors

// ---------------- generic direct conv, OCB output channels per thread -------
// out[(oc)*ostride + obase + sp],  weights OIHW, bias per-oc, optional ReLU.
template<int KH, int KW, int S, int OCB, int ACT>
__global__ __launch_bounds__(256) void convk(
    const float* __restrict__ in, const float* __restrict__ wt,
    const float* __restrict__ bs, float* __restrict__ out,
    int IC, int IH, int IW, int OH, int OW, int ostride, int obase)
{
    int sp = blockIdx.x * 256 + threadIdx.x;
    if (sp >= OH * OW) return;
    int oc0 = blockIdx.y * OCB;
    int oy = sp / OW, ox = sp - oy * OW;
    int iy0 = oy * S, ix0 = ox * S;

    float acc[OCB];
#pragma unroll
    for (int o = 0; o < OCB; ++o) acc[o] = bs[oc0 + o];

    const int ICK = IC * KH * KW;
    for (int ic = 0; ic < IC; ++ic) {
        const float* ip = in + ((size_t)ic * IH + iy0) * IW + ix0;
        const float* wp = wt + (size_t)oc0 * ICK + ic * KH * KW;
#pragma unroll
        for (int ky = 0; ky < KH; ++ky) {
#pragma unroll
            for (int kx = 0; kx < KW; ++kx) {
                float x = ip[ky * IW + kx];          // coalesced across lanes
#pragma unroll
                for (int o = 0; o < OCB; ++o)         // wave-uniform weights -> s_load
                    acc[o] = fmaf(x, wp[o * ICK + ky * KW + kx], acc[o]);
            }
        }
    }
#pragma unroll
    for (int o = 0; o < OCB; ++o) {
        float r = acc[o];
        if (ACT == 1) r = fmaxf(r, 0.f);
        out[(size_t)(oc0 + o) * ostride + obase + sp] = r;
    }
}

// ---------------- u*v gated head: UV[j][n] = sigmoid(U h) * tanh(V h) -------
__global__ __launch_bounds__(256) void uv_kernel(
    const float* __restrict__ H, const float* __restrict__ Uw,
    const float* __restrict__ Ub, const float* __restrict__ Vw,
    const float* __restrict__ Vb, float* __restrict__ UV, int M, int N)
{
    int n = blockIdx.x * 256 + threadIdx.x;
    if (n >= N) return;
    int j0 = blockIdx.y * 8;
    float au[8], av[8];
#pragma unroll
    for (int j = 0; j < 8; ++j) { au[j] = Ub[j0 + j]; av[j] = Vb[j0 + j]; }
    for (int m = 0; m < M; ++m) {
        float h = H[(size_t)m * N + n];
#pragma unroll
        for (int j = 0; j < 8; ++j) {
            au[j] = fmaf(h, Uw[(j0 + j) * M + m], au[j]);
            av[j] = fmaf(h, Vw[(j0 + j) * M + m], av[j]);
        }
    }
#pragma unroll
    for (int j = 0; j < 8; ++j) {
        float u = 1.f / (1.f + expf(-au[j]));
        float v = tanhf(av[j]);
        UV[(size_t)(j0 + j) * N + n] = u * v;
    }
}

// ---------------- att[n] = sigmoid(Wa . UV[:,n] + b) ------------------------
__global__ __launch_bounds__(256) void att_kernel(
    const float* __restrict__ UV, const float* __restrict__ Waw,
    const float* __restrict__ Wab, float* __restrict__ att, int J, int N)
{
    int n = blockIdx.x * 256 + threadIdx.x;
    if (n >= N) return;
    float s = Wab[0];
    for (int j = 0; j < J; ++j) s = fmaf(UV[(size_t)j * N + n], Waw[j], s);
    att[n] = 1.f / (1.f + expf(-s));
}

// ---------------- rank (stable descending) -> cluster id --------------------
__global__ __launch_bounds__(256) void rank_kernel(
    const float* __restrict__ att, int* __restrict__ cid, int N)
{
    __shared__ float sa[1024];
    int n = blockIdx.x * 256 + threadIdx.x;
    float a = (n < N) ? att[n] : 0.f;
    int r = 0;
    for (int base = 0; base < N; base += 1024) {
        int cnt = min(1024, N - base);
        for (int t = threadIdx.x; t < cnt; t += 256) sa[t] = att[base + t];
        __syncthreads();
        if (n < N) {
            for (int t = 0; t < cnt; ++t) {
                float aj = sa[t];
                int j = base + t;
                r += (int)(aj > a) | ((int)(aj == a) & (int)(j < n));
            }
        }
        __syncthreads();
    }
    if (n < N) cid[n] = (r * 10) / N;
}

// ---------------- fc_raw[k][m] = sum_{cid[n]==k} H[m][n]*att[n] -------------
__global__ __launch_bounds__(256) void fc_reduce(
    const float* __restrict__ H, const float* __restrict__ att,
    const int* __restrict__ cid, float* __restrict__ fc_raw, int N)
{
    int m = blockIdx.x;
    const float* Hm = H + (size_t)m * N;
    float acc[10];
#pragma unroll
    for (int k = 0; k < 10; ++k) acc[k] = 0.f;
    for (int n = threadIdx.x; n < N; n += 256) {
        float hw = Hm[n] * att[n];
        int c = cid[n];
#pragma unroll
        for (int k = 0; k < 10; ++k) acc[k] += (c == k) ? hw : 0.f;
    }
    __shared__ float red[256];
#pragma unroll
    for (int k = 0; k < 10; ++k) {
        red[threadIdx.x] = acc[k];
        __syncthreads();
        for (int s = 128; s > 0; s >>= 1) {
            if (threadIdx.x < s) red[threadIdx.x] += red[threadIdx.x + s];
            __syncthreads();
        }
        if (threadIdx.x == 0) fc_raw[k * 512 + m] = red[0];
        __syncthreads();
    }
}

// ---------------- sw[k], pc_raw[k][4] (coords computed analytically) --------
__device__ __forceinline__ void anchor_coords(int n, float& cx, float& cy,
                                              float& bw, float& bh)
{
    int kh, kw, Wa, loc;
    if (n < 3721)       { kh = 3; kw = 3; Wa = 61; loc = n; }
    else if (n < 7690)  { kh = 1; kw = 1; Wa = 63; loc = n - 3721; }
    else if (n < 11533) { kh = 3; kw = 1; Wa = 63; loc = n - 7690; }
    else                { kh = 1; kw = 3; Wa = 61; loc = n - 11533; }
    int iy = loc / Wa, ix = loc - iy * Wa;
    cx = (ix + kw * 0.5f) * (1.f / 63.f);
    cy = (iy + kh * 0.5f) * (1.f / 63.f);
    bw = kw * (1.f / 63.f);
    bh = kh * (1.f / 63.f);
}

__global__ __launch_bounds__(256) void swpc_kernel(
    const float* __restrict__ att, const int* __restrict__ cid,
    float* __restrict__ sw, float* __restrict__ pc_raw, int N)
{
    float asw[10], ax[10], ay[10], aw[10], ah[10];
#pragma unroll
    for (int k = 0; k < 10; ++k) { asw[k] = ax[k] = ay[k] = aw[k] = ah[k] = 0.f; }
    for (int n = threadIdx.x; n < N; n += 256) {
        float a = att[n];
        int c = cid[n];
        float cx, cy, bw, bh;
        anchor_coords(n, cx, cy, bw, bh);
#pragma unroll
        for (int k = 0; k < 10; ++k) {
            float sel = (c == k) ? a : 0.f;
            asw[k] += sel;
            ax[k] = fmaf(sel, cx, ax[k]);
            ay[k] = fmaf(sel, cy, ay[k]);
            aw[k] = fmaf(sel, bw, aw[k]);
            ah[k] = fmaf(sel, bh, ah[k]);
        }
    }
    __shared__ float red[256];
#define RED_STORE(val, dst)                                                    \
    {                                                                          \
        red[threadIdx.x] = (val);                                              \
        __syncthreads();                                                       \
        for (int s = 128; s > 0; s >>= 1) {                                    \
            if (threadIdx.x < s) red[threadIdx.x] += red[threadIdx.x + s];     \
            __syncthreads();                                                   \
        }                                                                      \
        if (threadIdx.x == 0) (dst) = red[0];                                  \
        __syncthreads();                                                       \
    }
#pragma unroll
    for (int k = 0; k < 10; ++k) {
        RED_STORE(asw[k], sw[k]);
        RED_STORE(ax[k], pc_raw[k * 4 + 0]);
        RED_STORE(ay[k], pc_raw[k * 4 + 1]);
        RED_STORE(aw[k], pc_raw[k * 4 + 2]);
        RED_STORE(ah[k], pc_raw[k * 4 + 3]);
    }
#undef RED_STORE
}

// ---------------- cluster softmax head, logits, final outputs ---------------
__global__ __launch_bounds__(512) void final_kernel(
    const float* __restrict__ fc_raw, const float* __restrict__ sw,
    const float* __restrict__ pc_raw, const float* __restrict__ cluster_w,
    const float* __restrict__ cluster_b, const float* __restrict__ cls_w,
    const float* __restrict__ cls_b, float* __restrict__ out)
{
    __shared__ float red[512];
    int t = threadIdx.x;   // 512 threads, t == feature index m

    float fcn[10];
#pragma unroll
    for (int k = 0; k < 10; ++k)
        fcn[k] = fc_raw[k * 512 + t] / (sw[k] + 1e-8f);

    float cw = cluster_w[t];
    float sc[10];
#pragma unroll
    for (int k = 0; k < 10; ++k) {
        red[t] = fcn[k] * cw;
        __syncthreads();
        for (int s = 256; s > 0; s >>= 1) {
            if (t < s) red[t] += red[t + s];
            __syncthreads();
        }
        sc[k] = red[0] + cluster_b[0];
        __syncthreads();
    }
    // softmax over clusters (uniform in every thread)
    float mx = sc[0];
#pragma unroll
    for (int k = 1; k < 10; ++k) mx = fmaxf(mx, sc[k]);
    float se = 0.f;
#pragma unroll
    for (int k = 0; k < 10; ++k) { sc[k] = expf(sc[k] - mx); se += sc[k]; }
    float inv = 1.f / se;
#pragma unroll
    for (int k = 0; k < 10; ++k) sc[k] *= inv;   // att_c

    float fm = 0.f;
#pragma unroll
    for (int k = 0; k < 10; ++k) fm = fmaf(sc[k], fcn[k], fm);  // final[t]

    float lg[10];
#pragma unroll
    for (int c = 0; c < 10; ++c) {
        red[t] = fm * cls_w[c * 512 + t];
        __syncthreads();
        for (int s = 256; s > 0; s >>= 1) {
            if (t < s) red[t] += red[t + s];
            __syncthreads();
        }
        lg[c] = red[0] + cls_b[c];
        __syncthreads();
    }
    float mx2 = lg[0];
#pragma unroll
    for (int c = 1; c < 10; ++c) mx2 = fmaxf(mx2, lg[c]);
    float se2 = 0.f;
#pragma unroll
    for (int c = 0; c < 10; ++c) { lg[c] = expf(lg[c] - mx2); se2 += lg[c]; }
    float inv2 = 1.f / se2;

    if (t < 10) out[t] = lg[t] * inv2;           // softmax(logits)
    if (t >= 10 && t < 20) out[t] = sc[t - 10];  // att_c
    if (t >= 20 && t < 60) {
        int i = t - 20;
        out[t] = pc_raw[i] / (sw[i >> 2] + 1e-8f);  // pc
    }
}

// ---------------------------------------------------------------------------
extern "C" void kernel_launch(void* const* d_in, const int* in_sizes, int n_in,
                              void* d_out, int out_size, void* d_ws, size_t ws_size,
                              hipStream_t stream)
{
    const float* x       = (const float*)d_in[0];
    const float* c1w     = (const float*)d_in[1];
    const float* c1b     = (const float*)d_in[2];
    const float* c2w     = (const float*)d_in[3];
    const float* c2b     = (const float*)d_in[4];
    const float* c3w     = (const float*)d_in[5];
    const float* c3b     = (const float*)d_in[6];
    const float* a0w     = (const float*)d_in[7];
    const float* a0b     = (const float*)d_in[8];
    const float* a1w     = (const float*)d_in[9];
    const float* a1b     = (const float*)d_in[10];
    const float* a2w     = (const float*)d_in[11];
    const float* a2b     = (const float*)d_in[12];
    const float* a3w     = (const float*)d_in[13];
    const float* a3b     = (const float*)d_in[14];
    const float* W1w     = (const float*)d_in[15];
    const float* W1b     = (const float*)d_in[16];
    const float* Uw      = (const float*)d_in[17];
    const float* Ub      = (const float*)d_in[18];
    const float* Vw      = (const float*)d_in[19];
    const float* Vb      = (const float*)d_in[20];
    const float* Waw     = (const float*)d_in[21];
    const float* Wab     = (const float*)d_in[22];
    const float* clw     = (const float*)d_in[23];
    const float* clb     = (const float*)d_in[24];
    const float* clsw    = (const float*)d_in[25];
    const float* clsb    = (const float*)d_in[26];
    float* out = (float*)d_out;

    // workspace layout (floats); H overlays h1, UV overlays h2 (dead by then)
    float* ws  = (float*)d_ws;
    float* h1  = ws;               // 128*255*255 = 8,323,200
    float* h2  = ws + 8323200;     // 256*127*127 = 4,129,024
    float* h3  = ws + 12452224;    // 512*63*63   = 2,032,128
    float* A   = ws + 14484352;    // 1024*15376  = 15,745,024
    float* H   = h1;               // 512*15376   = 7,872,512 (fits in h1)
    float* UV  = h2;               // 256*15376   = 3,936,256 (fits in h2)
    float* att = ws + 30229376;    // 15376
    int*   cid = (int*)(ws + 30244752);  // 15376
    float* fcr = ws + 30260128;    // 10*512
    float* sw  = ws + 30265248;    // 10
    float* pcr = ws + 30265258;    // 10*4
    // total 30,265,298 floats ~= 121 MB

    dim3 blk(256);

    // backbone
    convk<3,3,2,8,0><<<dim3(255, 16), blk, 0, stream>>>(x,  c1w, c1b, h1, 3,   512, 512, 255, 255, 65025, 0);
    convk<3,3,2,8,0><<<dim3(64,  32), blk, 0, stream>>>(h1, c2w, c2b, h2, 128, 255, 255, 127, 127, 16129, 0);
    convk<3,3,2,8,0><<<dim3(16,  64), blk, 0, stream>>>(h2, c3w, c3b, h3, 256, 127, 127, 63,  63,  3969,  0);

    // anchor convs -> A[1024][15376] (channel-major == feat transpose)
    convk<3,3,1,8,0><<<dim3(15, 128), blk, 0, stream>>>(h3, a0w, a0b, A, 512, 63, 63, 61, 61, NTOT, 0);
    convk<1,1,1,8,0><<<dim3(16, 128), blk, 0, stream>>>(h3, a1w, a1b, A, 512, 63, 63, 63, 63, NTOT, 3721);
    convk<3,1,1,8,0><<<dim3(16, 128), blk, 0, stream>>>(h3, a2w, a2b, A, 512, 63, 63, 61, 63, NTOT, 7690);
    convk<1,3,1,8,0><<<dim3(16, 128), blk, 0, stream>>>(h3, a3w, a3b, A, 512, 63, 63, 63, 61, NTOT, 11533);

    // hmid = relu(W1 @ A)  -> H[512][15376]   (1x1-conv form of the GEMM)
    convk<1,1,1,8,1><<<dim3(61, 64), blk, 0, stream>>>(A, W1w, W1b, H, 1024, 1, NTOT, 1, NTOT, NTOT, 0);

    // UV = sigmoid(U H) * tanh(V H)   -> UV[256][15376]
    uv_kernel<<<dim3(61, 32), blk, 0, stream>>>(H, Uw, Ub, Vw, Vb, UV, 512, NTOT);

    // att[n]
    att_kernel<<<dim3(61), blk, 0, stream>>>(UV, Waw, Wab, att, 256, NTOT);

    // rank -> cluster ids
    rank_kernel<<<dim3(61), blk, 0, stream>>>(att, cid, NTOT);

    // segment reductions
    fc_reduce<<<dim3(512), blk, 0, stream>>>(H, att, cid, fcr, NTOT);
    swpc_kernel<<<dim3(1), blk, 0, stream>>>(att, cid, sw, pcr, NTOT);

    // head
    final_kernel<<<dim3(1), dim3(512), 0, stream>>>(fcr, sw, pcr, clw, clb, clsw, clsb, out);
}

// Round 2
// 1842.997 us; speedup vs baseline: 2.9577x; 2.9577x over previous
//
#include <hip/hip_runtime.h>
#include <math.h>

// ---------------------------------------------------------------------------
// Round 1: bf16 MFMA for anchors + W1 + UV (87.7 of 107 GFLOP).
// conv1/2/3 remain fp32 direct. h3 -> h3T (padded 65-grid, bf16) so all
// anchor convs are tap-shifted BT-GEMMs over the same B matrix.
// ---------------------------------------------------------------------------

#define NTOT 15376
typedef unsigned short u16;
typedef __attribute__((ext_vector_type(8))) short bf16x8;
typedef __attribute__((ext_vector_type(4))) float f32x4;

static __device__ __forceinline__ u16 f2bf(float x) {
    union { float f; unsigned u; } v; v.f = x;
    unsigned r = v.u + 0x7FFF + ((v.u >> 16) & 1);
    return (u16)(r >> 16);
}
static __device__ __forceinline__ float bf2f(u16 h) {
    union { unsigned u; float f; } v; v.u = ((unsigned)h) << 16;
    return v.f;
}

// ---------------- fp32 direct conv (round-0, verified) ----------------------
template<int KH, int KW, int S, int OCB, int ACT>
__global__ __launch_bounds__(256) void convk(
    const float* __restrict__ in, const float* __restrict__ wt,
    const float* __restrict__ bs, float* __restrict__ out,
    int IC, int IH, int IW, int OH, int OW, int ostride, int obase)
{
    int sp = blockIdx.x * 256 + threadIdx.x;
    if (sp >= OH * OW) return;
    int oc0 = blockIdx.y * OCB;
    int oy = sp / OW, ox = sp - oy * OW;
    int iy0 = oy * S, ix0 = ox * S;
    float acc[OCB];
#pragma unroll
    for (int o = 0; o < OCB; ++o) acc[o] = bs[oc0 + o];
    const int ICK = IC * KH * KW;
    for (int ic = 0; ic < IC; ++ic) {
        const float* ip = in + ((size_t)ic * IH + iy0) * IW + ix0;
        const float* wp = wt + (size_t)oc0 * ICK + ic * KH * KW;
#pragma unroll
        for (int ky = 0; ky < KH; ++ky)
#pragma unroll
            for (int kx = 0; kx < KW; ++kx) {
                float x = ip[ky * IW + kx];
#pragma unroll
                for (int o = 0; o < OCB; ++o)
                    acc[o] = fmaf(x, wp[o * ICK + ky * KW + kx], acc[o]);
            }
    }
#pragma unroll
    for (int o = 0; o < OCB; ++o) {
        float r = acc[o];
        if (ACT == 1) r = fmaxf(r, 0.f);
        out[(size_t)(oc0 + o) * ostride + obase + sp] = r;
    }
}

// ---------------- h3 [512][3969] f32 -> h3T [65-grid sp][512] bf16 ----------
__global__ __launch_bounds__(256) void transpose_h3(
    const float* __restrict__ h3, u16* __restrict__ h3T)
{
    __shared__ float tile[64][65];
    int nb = blockIdx.x * 64, cb = blockIdx.y * 64;
    int t = threadIdx.x;
    int ln = t & 63, q = t >> 6;
#pragma unroll 4
    for (int i = 0; i < 16; ++i) {
        int n = nb + ln, c = cb + q * 16 + i;
        tile[ln][q * 16 + i] = (n < 3969) ? h3[(long)c * 3969 + n] : 0.f;
    }
    __syncthreads();
    int lc = t & 63, q2 = t >> 6;
#pragma unroll 4
    for (int i = 0; i < 16; ++i) {
        int n = nb + q2 * 16 + i;
        if (n < 3969) {
            int np = (n / 63) * 65 + (n % 63);
            h3T[(long)np * 512 + cb + lc] = f2bf(tile[q2 * 16 + i][lc]);
        }
    }
}

// ---------------- weight packing -------------------------------------------
// dst[oc][t*IC+ic] = src[(oc*IC+ic)*NT + t]   (OIHW -> tap-major bf16)
__global__ __launch_bounds__(256) void pack_w(
    const float* __restrict__ src, u16* __restrict__ dst, int IC, int NT, long total)
{
    long i = (long)blockIdx.x * 256 + threadIdx.x;
    if (i >= total) return;
    int ic = (int)(i % IC);
    long r = i / IC;
    int t = (int)(r % NT);
    long oc = r / NT;
    dst[i] = f2bf(src[(oc * IC + ic) * NT + t]);
}

__global__ __launch_bounds__(256) void cast_bf(
    const float* __restrict__ src, u16* __restrict__ dst, long total)
{
    long i = (long)blockIdx.x * 256 + threadIdx.x;
    if (i < total) dst[i] = f2bf(src[i]);
}

// ---------------- the MFMA BT-GEMM -----------------------------------------
// C[M][n] = sum_k A[m][k] * B[row(n,tap)][c]   (B row-major [*][RSB] bf16)
// CMODE 0: n on 63x63 grid -> padded 65-grid rows ; CMODE 1: identity rows.
// TMODE tap schedule: 0:a0(3x3) 1:single 2:a2(3x1) 3:a3(1x3) 4:W1(K=1024)
// EMODE 0: bias -> bf16 scatter to Afeat[trg][M]  (valid-region mask)
//       1: bias+relu -> bf16 Hfeat[n][M]
//       2: bias+sigmoid/tanh (U/V halves) -> f32 UVT[n][M]
template<int CMODE, int EMODE, int TMODE>
__global__ __launch_bounds__(256) void gemm_bt(
    const u16* __restrict__ A, const u16* __restrict__ B,
    const float* __restrict__ bias0, const float* __restrict__ bias1,
    void* __restrict__ Cout, int M, int N, int RSB, int Ktot,
    int OH, int OW, int obase)
{
    __shared__ u16 As[8192];   // [128 m][64 k] swizzled, 16KB
    __shared__ u16 Bs[8192];   // [128 n][64 k] swizzled
    const int tid = threadIdx.x, w = tid >> 6, l = tid & 63;
    const int wr = w >> 1, wc = w & 1;
    const int n0 = blockIdx.x * 128, m0 = blockIdx.y * 128;
    const long RSA = (long)Ktot * 64;
    const int sl = l & 7, sh = l >> 3;       // slot, row&7

    int rloc[4], offB[4], wOff[4];
    long aRow[4];
#pragma unroll
    for (int j = 0; j < 4; ++j) {
        int r = w * 32 + j * 8 + sh;
        rloc[j] = r;
        int gn = n0 + r;
        if (CMODE == 0) { gn = min(gn, 3968); offB[j] = (gn / 63) * 65 + (gn % 63); }
        else            { offB[j] = min(gn, N - 1); }
        wOff[j] = r * 128 + ((sl ^ sh) * 16);
        aRow[j] = ((long)(m0 + r) * RSA + sl * 8) * 2;
    }

    f32x4 acc[4][4];
#pragma unroll
    for (int a = 0; a < 4; ++a)
#pragma unroll
        for (int b = 0; b < 4; ++b) acc[a][b] = (f32x4){0.f, 0.f, 0.f, 0.f};

    uint4 ra[4], rb[4];
#define GLOAD(kt)                                                              \
    {                                                                          \
        int t_ = (kt) >> 3, kb_ = (kt) & 7;                                    \
        int trow_, tcol_;                                                      \
        if (TMODE == 0)      { trow_ = (t_ / 3) * 65 + (t_ % 3); tcol_ = 0; }  \
        else if (TMODE == 1) { trow_ = 0; tcol_ = 0; (void)t_; }               \
        else if (TMODE == 2) { trow_ = t_ * 65; tcol_ = 0; }                   \
        else if (TMODE == 3) { trow_ = t_; tcol_ = 0; }                        \
        else                 { trow_ = 0; tcol_ = t_ * 512; }                  \
        long cbA_ = (long)(kt) * 128;                                          \
        long cbB_ = ((long)tcol_ + kb_ * 64 + sl * 8) * 2;                     \
        _Pragma("unroll")                                                      \
        for (int j = 0; j < 4; ++j) {                                          \
            ra[j] = *(const uint4*)((const char*)A + aRow[j] + cbA_);          \
            rb[j] = *(const uint4*)((const char*)B +                           \
                        (long)(offB[j] + trow_) * RSB * 2 + cbB_);             \
        }                                                                      \
    }

    GLOAD(0);
    for (int kt = 0; kt < Ktot; ++kt) {
        __syncthreads();
#pragma unroll
        for (int j = 0; j < 4; ++j) {
            *(uint4*)((char*)As + wOff[j]) = ra[j];
            *(uint4*)((char*)Bs + wOff[j]) = rb[j];
        }
        __syncthreads();
        if (kt + 1 < Ktot) GLOAD(kt + 1);
#pragma unroll
        for (int kk = 0; kk < 2; ++kk) {
            bf16x8 af[4], bfr[4];
#pragma unroll
            for (int f = 0; f < 4; ++f) {
                int rm = wr * 64 + f * 16 + (l & 15);
                af[f] = *(const bf16x8*)((const char*)As + rm * 128 +
                           (((kk * 4 + (l >> 4)) ^ (rm & 7)) * 16));
                int rn = wc * 64 + f * 16 + (l & 15);
                bfr[f] = *(const bf16x8*)((const char*)Bs + rn * 128 +
                           (((kk * 4 + (l >> 4)) ^ (rn & 7)) * 16));
            }
#pragma unroll
            for (int fm = 0; fm < 4; ++fm)
#pragma unroll
                for (int fn = 0; fn < 4; ++fn)
                    acc[fm][fn] = __builtin_amdgcn_mfma_f32_16x16x32_bf16(
                        af[fm], bfr[fn], acc[fm][fn], 0, 0, 0);
        }
    }
#undef GLOAD

    // epilogue
#pragma unroll
    for (int fm = 0; fm < 4; ++fm) {
        int gmb = m0 + wr * 64 + fm * 16 + (l >> 4) * 4;   // 4 consecutive m
#pragma unroll
        for (int fn = 0; fn < 4; ++fn) {
            int gn = n0 + wc * 64 + fn * 16 + (l & 15);
            f32x4 v = acc[fm][fn];
            if (EMODE == 0) {
                if (gn < 3969) {
                    int oy = gn / 63, ox = gn - oy * 63;
                    if (oy < OH && ox < OW) {
                        int trg = obase + oy * OW + ox;
                        float4 bv = *(const float4*)(bias0 + gmb);
                        unsigned long long pk =
                            (unsigned long long)f2bf(v.x + bv.x)
                          | ((unsigned long long)f2bf(v.y + bv.y) << 16)
                          | ((unsigned long long)f2bf(v.z + bv.z) << 32)
                          | ((unsigned long long)f2bf(v.w + bv.w) << 48);
                        *(unsigned long long*)((u16*)Cout + (long)trg * M + gmb) = pk;
                    }
                }
            } else if (EMODE == 1) {
                if (gn < N) {
                    float4 bv = *(const float4*)(bias0 + gmb);
                    unsigned long long pk =
                        (unsigned long long)f2bf(fmaxf(v.x + bv.x, 0.f))
                      | ((unsigned long long)f2bf(fmaxf(v.y + bv.y, 0.f)) << 16)
                      | ((unsigned long long)f2bf(fmaxf(v.z + bv.z, 0.f)) << 32)
                      | ((unsigned long long)f2bf(fmaxf(v.w + bv.w, 0.f)) << 48);
                    *(unsigned long long*)((u16*)Cout + (long)gn * M + gmb) = pk;
                }
            } else {
                if (gn < N) {
                    float4 o;
                    if (gmb < 256) {
                        float4 bv = *(const float4*)(bias0 + gmb);
                        o.x = 1.f / (1.f + expf(-(v.x + bv.x)));
                        o.y = 1.f / (1.f + expf(-(v.y + bv.y)));
                        o.z = 1.f / (1.f + expf(-(v.z + bv.z)));
                        o.w = 1.f / (1.f + expf(-(v.w + bv.w)));
                    } else {
                        float4 bv = *(const float4*)(bias1 + gmb - 256);
                        o.x = tanhf(v.x + bv.x); o.y = tanhf(v.y + bv.y);
                        o.z = tanhf(v.z + bv.z); o.w = tanhf(v.w + bv.w);
                    }
                    *(float4*)((float*)Cout + (long)gn * M + gmb) = o;
                }
            }
        }
    }
}

// ---------------- att[n] = sigmoid(sum_j Wa[j]*u[n][j]*v[n][j]) -------------
__global__ __launch_bounds__(256) void att_v2(
    const float* __restrict__ UVT, const float* __restrict__ Waw,
    const float* __restrict__ Wab, float* __restrict__ att, int N)
{
    int n = blockIdx.x * 256 + threadIdx.x;
    if (n >= N) return;
    const float* row = UVT + (long)n * 512;
    float s = Wab[0];
    for (int j = 0; j < 64; ++j) {
        float4 u4 = *(const float4*)(row + j * 4);
        float4 v4 = *(const float4*)(row + 256 + j * 4);
        float4 w4 = *(const float4*)(Waw + j * 4);
        s = fmaf(w4.x, u4.x * v4.x, s);
        s = fmaf(w4.y, u4.y * v4.y, s);
        s = fmaf(w4.z, u4.z * v4.z, s);
        s = fmaf(w4.w, u4.w * v4.w, s);
    }
    att[n] = 1.f / (1.f + expf(-s));
}

// ---------------- rank (stable descending) -> cluster id --------------------
__global__ __launch_bounds__(256) void rank_kernel(
    const float* __restrict__ att, int* __restrict__ cid, int N)
{
    __shared__ float sa[1024];
    int n = blockIdx.x * 256 + threadIdx.x;
    float a = (n < N) ? att[n] : 0.f;
    int r = 0;
    for (int base = 0; base < N; base += 1024) {
        int cnt = min(1024, N - base);
        for (int t = threadIdx.x; t < cnt; t += 256) sa[t] = att[base + t];
        __syncthreads();
        if (n < N) {
            for (int t = 0; t < cnt; ++t) {
                float aj = sa[t];
                int j = base + t;
                r += (int)(aj > a) | ((int)(aj == a) & (int)(j < n));
            }
        }
        __syncthreads();
    }
    if (n < N) cid[n] = (r * 10) / N;
}

// ---------------- fc_raw[k][m] from Hfeat bf16 ------------------------------
__global__ __launch_bounds__(256) void fc_reduce2(
    const u16* __restrict__ Hfeat, const float* __restrict__ att,
    const int* __restrict__ cid, float* __restrict__ fc_raw, int N)
{
    int m = blockIdx.x;
    float acc[10];
#pragma unroll
    for (int k = 0; k < 10; ++k) acc[k] = 0.f;
    for (int n = threadIdx.x; n < N; n += 256) {
        float hw = bf2f(Hfeat[(long)n * 512 + m]) * att[n];
        int c = cid[n];
#pragma unroll
        for (int k = 0; k < 10; ++k) acc[k] += (c == k) ? hw : 0.f;
    }
    __shared__ float red[256];
#pragma unroll
    for (int k = 0; k < 10; ++k) {
        red[threadIdx.x] = acc[k];
        __syncthreads();
        for (int s = 128; s > 0; s >>= 1) {
            if (threadIdx.x < s) red[threadIdx.x] += red[threadIdx.x + s];
            __syncthreads();
        }
        if (threadIdx.x == 0) fc_raw[k * 512 + m] = red[0];
        __syncthreads();
    }
}

// ---------------- sw[k], pc_raw[k][4] ---------------------------------------
__device__ __forceinline__ void anchor_coords(int n, float& cx, float& cy,
                                              float& bw, float& bh)
{
    int kh, kw, Wa, loc;
    if (n < 3721)       { kh = 3; kw = 3; Wa = 61; loc = n; }
    else if (n < 7690)  { kh = 1; kw = 1; Wa = 63; loc = n - 3721; }
    else if (n < 11533) { kh = 3; kw = 1; Wa = 63; loc = n - 7690; }
    else                { kh = 1; kw = 3; Wa = 61; loc = n - 11533; }
    int iy = loc / Wa, ix = loc - iy * Wa;
    cx = (ix + kw * 0.5f) * (1.f / 63.f);
    cy = (iy + kh * 0.5f) * (1.f / 63.f);
    bw = kw * (1.f / 63.f);
    bh = kh * (1.f / 63.f);
}

__global__ __launch_bounds__(256) void swpc_kernel(
    const float* __restrict__ att, const int* __restrict__ cid,
    float* __restrict__ sw, float* __restrict__ pc_raw, int N)
{
    float asw[10], ax[10], ay[10], aw[10], ah[10];
#pragma unroll
    for (int k = 0; k < 10; ++k) { asw[k] = ax[k] = ay[k] = aw[k] = ah[k] = 0.f; }
    for (int n = threadIdx.x; n < N; n += 256) {
        float a = att[n];
        int c = cid[n];
        float cx, cy, bw, bh;
        anchor_coords(n, cx, cy, bw, bh);
#pragma unroll
        for (int k = 0; k < 10; ++k) {
            float sel = (c == k) ? a : 0.f;
            asw[k] += sel;
            ax[k] = fmaf(sel, cx, ax[k]);
            ay[k] = fmaf(sel, cy, ay[k]);
            aw[k] = fmaf(sel, bw, aw[k]);
            ah[k] = fmaf(sel, bh, ah[k]);
        }
    }
    __shared__ float red[256];
#define RED_STORE(val, dst)                                                    \
    {                                                                          \
        red[threadIdx.x] = (val);                                              \
        __syncthreads();                                                       \
        for (int s = 128; s > 0; s >>= 1) {                                    \
            if (threadIdx.x < s) red[threadIdx.x] += red[threadIdx.x + s];     \
            __syncthreads();                                                   \
        }                                                                      \
        if (threadIdx.x == 0) (dst) = red[0];                                  \
        __syncthreads();                                                       \
    }
#pragma unroll
    for (int k = 0; k < 10; ++k) {
        RED_STORE(asw[k], sw[k]);
        RED_STORE(ax[k], pc_raw[k * 4 + 0]);
        RED_STORE(ay[k], pc_raw[k * 4 + 1]);
        RED_STORE(aw[k], pc_raw[k * 4 + 2]);
        RED_STORE(ah[k], pc_raw[k * 4 + 3]);
    }
#undef RED_STORE
}

// ---------------- head ------------------------------------------------------
__global__ __launch_bounds__(512) void final_kernel(
    const float* __restrict__ fc_raw, const float* __restrict__ sw,
    const float* __restrict__ pc_raw, const float* __restrict__ cluster_w,
    const float* __restrict__ cluster_b, const float* __restrict__ cls_w,
    const float* __restrict__ cls_b, float* __restrict__ out)
{
    __shared__ float red[512];
    int t = threadIdx.x;
    float fcn[10];
#pragma unroll
    for (int k = 0; k < 10; ++k)
        fcn[k] = fc_raw[k * 512 + t] / (sw[k] + 1e-8f);
    float cw = cluster_w[t];
    float sc[10];
#pragma unroll
    for (int k = 0; k < 10; ++k) {
        red[t] = fcn[k] * cw;
        __syncthreads();
        for (int s = 256; s > 0; s >>= 1) {
            if (t < s) red[t] += red[t + s];
            __syncthreads();
        }
        sc[k] = red[0] + cluster_b[0];
        __syncthreads();
    }
    float mx = sc[0];
#pragma unroll
    for (int k = 1; k < 10; ++k) mx = fmaxf(mx, sc[k]);
    float se = 0.f;
#pragma unroll
    for (int k = 0; k < 10; ++k) { sc[k] = expf(sc[k] - mx); se += sc[k]; }
    float inv = 1.f / se;
#pragma unroll
    for (int k = 0; k < 10; ++k) sc[k] *= inv;
    float fm = 0.f;
#pragma unroll
    for (int k = 0; k < 10; ++k) fm = fmaf(sc[k], fcn[k], fm);
    float lg[10];
#pragma unroll
    for (int c = 0; c < 10; ++c) {
        red[t] = fm * cls_w[c * 512 + t];
        __syncthreads();
        for (int s = 256; s > 0; s >>= 1) {
            if (t < s) red[t] += red[t + s];
            __syncthreads();
        }
        lg[c] = red[0] + cls_b[c];
        __syncthreads();
    }
    float mx2 = lg[0];
#pragma unroll
    for (int c = 1; c < 10; ++c) mx2 = fmaxf(mx2, lg[c]);
    float se2 = 0.f;
#pragma unroll
    for (int c = 0; c < 10; ++c) { lg[c] = expf(lg[c] - mx2); se2 += lg[c]; }
    float inv2 = 1.f / se2;
    if (t < 10) out[t] = lg[t] * inv2;
    if (t >= 10 && t < 20) out[t] = sc[t - 10];
    if (t >= 20 && t < 60) {
        int i = t - 20;
        out[t] = pc_raw[i] / (sw[i >> 2] + 1e-8f);
    }
}

// ---------------------------------------------------------------------------
extern "C" void kernel_launch(void* const* d_in, const int* in_sizes, int n_in,
                              void* d_out, int out_size, void* d_ws, size_t ws_size,
                              hipStream_t stream)
{
    const float* x    = (const float*)d_in[0];
    const float* c1w  = (const float*)d_in[1];   const float* c1b = (const float*)d_in[2];
    const float* c2w  = (const float*)d_in[3];   const float* c2b = (const float*)d_in[4];
    const float* c3w  = (const float*)d_in[5];   const float* c3b = (const float*)d_in[6];
    const float* a0w  = (const float*)d_in[7];   const float* a0b = (const float*)d_in[8];
    const float* a1w  = (const float*)d_in[9];   const float* a1b = (const float*)d_in[10];
    const float* a2w  = (const float*)d_in[11];  const float* a2b = (const float*)d_in[12];
    const float* a3w  = (const float*)d_in[13];  const float* a3b = (const float*)d_in[14];
    const float* W1w  = (const float*)d_in[15];  const float* W1b = (const float*)d_in[16];
    const float* Uw   = (const float*)d_in[17];  const float* Ub  = (const float*)d_in[18];
    const float* Vw   = (const float*)d_in[19];  const float* Vb  = (const float*)d_in[20];
    const float* Waw  = (const float*)d_in[21];  const float* Wab = (const float*)d_in[22];
    const float* clw  = (const float*)d_in[23];  const float* clb = (const float*)d_in[24];
    const float* clsw = (const float*)d_in[25];  const float* clsb= (const float*)d_in[26];
    float* out = (float*)d_out;

    // ---- workspace layout (float units), with overlays -------------------
    float* ws = (float*)d_ws;
    float* h1   = ws;                       // 8,323,200 f  (conv1 out)
    u16*   Afeat= (u16*)ws;                 //   overlays h1 after conv2
    float* h2   = ws + 8323200;             // 4,129,024 f  (conv2 out)
    u16*   Hfeat= (u16*)(ws + 8323200);     //   overlays h2 after conv3
    float* h3   = ws + 12452224;            // 2,032,128 f
    u16*   h3T  = (u16*)(ws + 14484352);    // 4225*512 bf16 = 1,081,600 f
    float* UVT  = ws + 15565952;            // 15376*512 f   = 7,872,512 f
    u16*   Wpk  = (u16*)(ws + 23438464);    // 16*1024*512 bf16 = 4,194,304 f
    u16*   W1pk = (u16*)(ws + 27632768);    // 512*1024 bf16 = 262,144 f
    u16*   UVpk = (u16*)(ws + 27894912);    // 512*512 bf16  = 131,072 f
    float* att  = ws + 28025984;            // 15,376
    int*   cid  = (int*)(ws + 28041360);    // 15,376
    float* fcr  = ws + 28056736;            // 5,120
    float* sw   = ws + 28061856;            // 10
    float* pcr  = ws + 28061866;            // 40
    // total ~28.06M floats = 112.3 MB

    u16* Wpk0 = Wpk;                 // a0: [1024][9*512]
    u16* Wpk1 = Wpk + 4718592;       // a1: [1024][512]
    u16* Wpk2 = Wpk + 5242880;       // a2: [1024][3*512]
    u16* Wpk3 = Wpk + 6815744;       // a3: [1024][3*512]

    dim3 blk(256);

    // ---- weight packing / casts ------------------------------------------
    pack_w<<<dim3(18432), blk, 0, stream>>>(a0w, Wpk0, 512, 9, 4718592L);
    pack_w<<<dim3(2048),  blk, 0, stream>>>(a1w, Wpk1, 512, 1, 524288L);
    pack_w<<<dim3(6144),  blk, 0, stream>>>(a2w, Wpk2, 512, 3, 1572864L);
    pack_w<<<dim3(6144),  blk, 0, stream>>>(a3w, Wpk3, 512, 3, 1572864L);
    cast_bf<<<dim3(2048), blk, 0, stream>>>(W1w, W1pk, 524288L);
    cast_bf<<<dim3(512),  blk, 0, stream>>>(Uw, UVpk, 131072L);
    cast_bf<<<dim3(512),  blk, 0, stream>>>(Vw, UVpk + 131072, 131072L);

    // ---- backbone (fp32 direct) ------------------------------------------
    convk<3,3,2,8,0><<<dim3(255, 16), blk, 0, stream>>>(x,  c1w, c1b, h1, 3,   512, 512, 255, 255, 65025, 0);
    convk<3,3,2,8,0><<<dim3(64,  32), blk, 0, stream>>>(h1, c2w, c2b, h2, 128, 255, 255, 127, 127, 16129, 0);
    convk<3,3,2,8,0><<<dim3(16,  64), blk, 0, stream>>>(h2, c3w, c3b, h3, 256, 127, 127, 63,  63,  3969,  0);

    // ---- h3 -> h3T (padded 65-grid, bf16) --------------------------------
    transpose_h3<<<dim3(63, 8), blk, 0, stream>>>(h3, h3T);

    // ---- anchor GEMMs -> Afeat[n][1024] bf16 -----------------------------
    gemm_bt<0,0,0><<<dim3(32, 8), blk, 0, stream>>>(Wpk0, h3T, a0b, nullptr, Afeat, 1024, 3969, 512, 72, 61, 61, 0);
    gemm_bt<0,0,1><<<dim3(32, 8), blk, 0, stream>>>(Wpk1, h3T, a1b, nullptr, Afeat, 1024, 3969, 512, 8,  63, 63, 3721);
    gemm_bt<0,0,2><<<dim3(32, 8), blk, 0, stream>>>(Wpk2, h3T, a2b, nullptr, Afeat, 1024, 3969, 512, 24, 61, 63, 7690);
    gemm_bt<0,0,3><<<dim3(32, 8), blk, 0, stream>>>(Wpk3, h3T, a3b, nullptr, Afeat, 1024, 3969, 512, 24, 63, 61, 11533);

    // ---- W1 GEMM: Hfeat[n][512] = relu(W1 @ feat + b), bf16 --------------
    gemm_bt<1,1,4><<<dim3(121, 4), blk, 0, stream>>>(W1pk, Afeat, W1b, nullptr, Hfeat, 512, NTOT, 1024, 16, 0, 0, 0);

    // ---- UV GEMM: UVT[n][512] = {sigmoid(U h), tanh(V h)}, fp32 ----------
    gemm_bt<1,2,1><<<dim3(121, 4), blk, 0, stream>>>(UVpk, Hfeat, Ub, Vb, UVT, 512, NTOT, 512, 8, 0, 0, 0);

    // ---- attention, rank, reductions, head -------------------------------
    att_v2<<<dim3(61), blk, 0, stream>>>(UVT, Waw, Wab, att, NTOT);
    rank_kernel<<<dim3(61), blk, 0, stream>>>(att, cid, NTOT);
    fc_reduce2<<<dim3(512), blk, 0, stream>>>(Hfeat, att, cid, fcr, NTOT);
    swpc_kernel<<<dim3(1), blk, 0, stream>>>(att, cid, sw, pcr, NTOT);
    final_kernel<<<dim3(1), dim3(512), 0, stream>>>(fcr, sw, pcr, clw, clb, clsw, clsb, out);
}

// Round 3
// 1256.460 us; speedup vs baseline: 4.3383x; 1.4668x over previous
//
#include <hip/hip_runtime.h>
#include <math.h>

// ---------------------------------------------------------------------------
// Round 2: conv2/conv3 moved onto the bf16 MFMA BT-GEMM engine (tap-shifted
// rows, stride-2 mapping). conv1 stays fp32 direct (K=27) but writes bf16
// h1T[sp][128] directly. h3 fp32 buffer + transpose kernel eliminated:
// conv3 GEMM epilogue scatters into padded h3T.
// ---------------------------------------------------------------------------

#define NTOT 15376
typedef unsigned short u16;
typedef unsigned long long u64;
typedef __attribute__((ext_vector_type(8))) short bf16x8;
typedef __attribute__((ext_vector_type(4))) float f32x4;

static __device__ __forceinline__ u16 f2bf(float x) {
    union { float f; unsigned u; } v; v.f = x;
    unsigned r = v.u + 0x7FFF + ((v.u >> 16) & 1);
    return (u16)(r >> 16);
}
static __device__ __forceinline__ float bf2f(u16 h) {
    union { unsigned u; float f; } v; v.u = ((unsigned)h) << 16;
    return v.f;
}

// ---------------- conv1: fp32 direct, OCB=16, bf16 transposed output --------
__global__ __launch_bounds__(256) void conv1k(
    const float* __restrict__ in, const float* __restrict__ wt,
    const float* __restrict__ bs, u16* __restrict__ h1T)
{
    int sp = blockIdx.x * 256 + threadIdx.x;
    if (sp >= 255 * 255) return;
    int oc0 = blockIdx.y * 16;
    int oy = sp / 255, ox = sp - oy * 255;
    const float* ip = in + (long)oy * 2 * 512 + ox * 2;
    float acc[16];
#pragma unroll
    for (int o = 0; o < 16; ++o) acc[o] = bs[oc0 + o];
#pragma unroll
    for (int ic = 0; ic < 3; ++ic)
#pragma unroll
        for (int ky = 0; ky < 3; ++ky)
#pragma unroll
            for (int kx = 0; kx < 3; ++kx) {
                float x = ip[ic * 262144 + ky * 512 + kx];
                const float* wp = wt + oc0 * 27 + ic * 9 + ky * 3 + kx;
#pragma unroll
                for (int o = 0; o < 16; ++o)
                    acc[o] = fmaf(x, wp[o * 27], acc[o]);
            }
    u16* dst = h1T + (long)sp * 128 + oc0;
#pragma unroll
    for (int g = 0; g < 4; ++g) {
        u64 pk = (u64)f2bf(acc[g * 4 + 0])
               | ((u64)f2bf(acc[g * 4 + 1]) << 16)
               | ((u64)f2bf(acc[g * 4 + 2]) << 32)
               | ((u64)f2bf(acc[g * 4 + 3]) << 48);
        *(u64*)(dst + g * 4) = pk;
    }
}

// ---------------- weight packing -------------------------------------------
// dst[(oc*NT + t)*IC + ic] = src[(oc*IC+ic)*NT + t]   (OIHW -> tap-major bf16)
__global__ __launch_bounds__(256) void pack_w(
    const float* __restrict__ src, u16* __restrict__ dst, int IC, int NT, long total)
{
    long i = (long)blockIdx.x * 256 + threadIdx.x;
    if (i >= total) return;
    int ic = (int)(i % IC);
    long r = i / IC;
    int t = (int)(r % NT);
    long oc = r / NT;
    dst[i] = f2bf(src[(oc * IC + ic) * NT + t]);
}

__global__ __launch_bounds__(256) void cast_bf(
    const float* __restrict__ src, u16* __restrict__ dst, long total)
{
    long i = (long)blockIdx.x * 256 + threadIdx.x;
    if (i < total) dst[i] = f2bf(src[i]);
}

// ---------------- the MFMA BT-GEMM -----------------------------------------
// C[m][gn] = sum_k A[m][k] * B[offB(gn)+trow(tap)][.]   (B row-major bf16)
// CMODE: 0 anchors 63->65pad | 1 identity | 2 stride2@255(OW127) | 3 stride2@127(OW63)
// TMODE: 0 a0 3x3 IC512 | 1 single-tap | 2 a2 3x1 | 3 a3 1x3 | 4 W1 K1024
//        5 conv2 3x3 IC128 | 6 conv3 3x3 IC256
// EMODE: 0 bias->bf16 scatter Afeat (valid mask) | 1 bias+relu bf16 [gn][M]
//        2 bias+sig/tanh f32 [gn][M] | 3 bias bf16 scatter h3T 65pad | 4 bias bf16 [gn][M]
template<int CMODE, int EMODE, int TMODE>
__global__ __launch_bounds__(256) void gemm_bt(
    const u16* __restrict__ A, const u16* __restrict__ B,
    const float* __restrict__ bias0, const float* __restrict__ bias1,
    void* __restrict__ Cout, int M, int N, int RSB, int Ktot,
    int OH, int OW, int obase)
{
    __shared__ u16 As[8192];   // [128 m][64 k] swizzled, 16KB
    __shared__ u16 Bs[8192];   // [128 n][64 k] swizzled
    const int tid = threadIdx.x, w = tid >> 6, l = tid & 63;
    const int wr = w >> 1, wc = w & 1;
    const int n0 = blockIdx.x * 128, m0 = blockIdx.y * 128;
    const long RSA = (long)Ktot * 64;
    const int sl = l & 7, sh = l >> 3;
    constexpr int ICL2 = (TMODE == 5) ? 1 : (TMODE == 6) ? 2 : 3;
    constexpr int KBM  = (1 << ICL2) - 1;

    int offB[4], wOff[4];
    long aRow[4];
#pragma unroll
    for (int j = 0; j < 4; ++j) {
        int r = w * 32 + j * 8 + sh;
        int gn = n0 + r;
        if (CMODE == 0)      { gn = min(gn, 3968);  offB[j] = (gn / 63) * 65 + (gn % 63); }
        else if (CMODE == 1) { offB[j] = min(gn, N - 1); }
        else if (CMODE == 2) { gn = min(gn, 16128); offB[j] = (gn / 127) * 510 + (gn % 127) * 2; }
        else                 { gn = min(gn, 3968);  offB[j] = (gn / 63) * 254 + (gn % 63) * 2; }
        wOff[j] = r * 128 + ((sl ^ sh) * 16);
        aRow[j] = ((long)(m0 + r) * RSA + sl * 8) * 2;
    }

    f32x4 acc[4][4];
#pragma unroll
    for (int a = 0; a < 4; ++a)
#pragma unroll
        for (int b = 0; b < 4; ++b) acc[a][b] = (f32x4){0.f, 0.f, 0.f, 0.f};

    uint4 ra[4], rb[4];
#define GLOAD(kt)                                                              \
    {                                                                          \
        int t_ = (kt) >> ICL2, kb_ = (kt) & KBM;                               \
        int trow_ = 0, tcol_ = 0;                                              \
        if (TMODE == 0)      { trow_ = (t_ / 3) * 65 + (t_ % 3); }             \
        else if (TMODE == 2) { trow_ = t_ * 65; }                              \
        else if (TMODE == 3) { trow_ = t_; }                                   \
        else if (TMODE == 4) { tcol_ = t_ * 512; }                             \
        else if (TMODE == 5) { trow_ = (t_ / 3) * 255 + (t_ % 3); }            \
        else if (TMODE == 6) { trow_ = (t_ / 3) * 127 + (t_ % 3); }            \
        long cbA_ = (long)(kt) * 128;                                          \
        long cbB_ = ((long)tcol_ + kb_ * 64 + sl * 8) * 2;                     \
        _Pragma("unroll")                                                      \
        for (int j = 0; j < 4; ++j) {                                          \
            ra[j] = *(const uint4*)((const char*)A + aRow[j] + cbA_);          \
            rb[j] = *(const uint4*)((const char*)B +                           \
                        (long)(offB[j] + trow_) * RSB * 2 + cbB_);             \
        }                                                                      \
    }

    GLOAD(0);
    for (int kt = 0; kt < Ktot; ++kt) {
        __syncthreads();
#pragma unroll
        for (int j = 0; j < 4; ++j) {
            *(uint4*)((char*)As + wOff[j]) = ra[j];
            *(uint4*)((char*)Bs + wOff[j]) = rb[j];
        }
        __syncthreads();
        if (kt + 1 < Ktot) GLOAD(kt + 1);
#pragma unroll
        for (int kk = 0; kk < 2; ++kk) {
            bf16x8 af[4], bfr[4];
#pragma unroll
            for (int f = 0; f < 4; ++f) {
                int rm = wr * 64 + f * 16 + (l & 15);
                af[f] = *(const bf16x8*)((const char*)As + rm * 128 +
                           (((kk * 4 + (l >> 4)) ^ (rm & 7)) * 16));
                int rn = wc * 64 + f * 16 + (l & 15);
                bfr[f] = *(const bf16x8*)((const char*)Bs + rn * 128 +
                           (((kk * 4 + (l >> 4)) ^ (rn & 7)) * 16));
            }
#pragma unroll
            for (int fm = 0; fm < 4; ++fm)
#pragma unroll
                for (int fn = 0; fn < 4; ++fn)
                    acc[fm][fn] = __builtin_amdgcn_mfma_f32_16x16x32_bf16(
                        af[fm], bfr[fn], acc[fm][fn], 0, 0, 0);
        }
    }
#undef GLOAD

    // epilogue
#pragma unroll
    for (int fm = 0; fm < 4; ++fm) {
        int gmb = m0 + wr * 64 + fm * 16 + (l >> 4) * 4;   // 4 consecutive m
#pragma unroll
        for (int fn = 0; fn < 4; ++fn) {
            int gn = n0 + wc * 64 + fn * 16 + (l & 15);
            f32x4 v = acc[fm][fn];
            if (EMODE == 0) {
                if (gn < 3969) {
                    int oy = gn / 63, ox = gn - oy * 63;
                    if (oy < OH && ox < OW) {
                        int trg = obase + oy * OW + ox;
                        float4 bv = *(const float4*)(bias0 + gmb);
                        u64 pk = (u64)f2bf(v.x + bv.x)
                               | ((u64)f2bf(v.y + bv.y) << 16)
                               | ((u64)f2bf(v.z + bv.z) << 32)
                               | ((u64)f2bf(v.w + bv.w) << 48);
                        *(u64*)((u16*)Cout + (long)trg * M + gmb) = pk;
                    }
                }
            } else if (EMODE == 1) {
                if (gn < N) {
                    float4 bv = *(const float4*)(bias0 + gmb);
                    u64 pk = (u64)f2bf(fmaxf(v.x + bv.x, 0.f))
                           | ((u64)f2bf(fmaxf(v.y + bv.y, 0.f)) << 16)
                           | ((u64)f2bf(fmaxf(v.z + bv.z, 0.f)) << 32)
                           | ((u64)f2bf(fmaxf(v.w + bv.w, 0.f)) << 48);
                    *(u64*)((u16*)Cout + (long)gn * M + gmb) = pk;
                }
            } else if (EMODE == 2) {
                if (gn < N) {
                    float4 o;
                    if (gmb < 256) {
                        float4 bv = *(const float4*)(bias0 + gmb);
                        o.x = 1.f / (1.f + expf(-(v.x + bv.x)));
                        o.y = 1.f / (1.f + expf(-(v.y + bv.y)));
                        o.z = 1.f / (1.f + expf(-(v.z + bv.z)));
                        o.w = 1.f / (1.f + expf(-(v.w + bv.w)));
                    } else {
                        float4 bv = *(const float4*)(bias1 + gmb - 256);
                        o.x = tanhf(v.x + bv.x); o.y = tanhf(v.y + bv.y);
                        o.z = tanhf(v.z + bv.z); o.w = tanhf(v.w + bv.w);
                    }
                    *(float4*)((float*)Cout + (long)gn * M + gmb) = o;
                }
            } else if (EMODE == 3) {
                if (gn < 3969) {
                    int trg = (gn / 63) * 65 + (gn % 63);
                    float4 bv = *(const float4*)(bias0 + gmb);
                    u64 pk = (u64)f2bf(v.x + bv.x)
                           | ((u64)f2bf(v.y + bv.y) << 16)
                           | ((u64)f2bf(v.z + bv.z) << 32)
                           | ((u64)f2bf(v.w + bv.w) << 48);
                    *(u64*)((u16*)Cout + (long)trg * M + gmb) = pk;
                }
            } else {
                if (gn < N) {
                    float4 bv = *(const float4*)(bias0 + gmb);
                    u64 pk = (u64)f2bf(v.x + bv.x)
                           | ((u64)f2bf(v.y + bv.y) << 16)
                           | ((u64)f2bf(v.z + bv.z) << 32)
                           | ((u64)f2bf(v.w + bv.w) << 48);
                    *(u64*)((u16*)Cout + (long)gn * M + gmb) = pk;
                }
            }
        }
    }
}

// ---------------- att[n] = sigmoid(sum_j Wa[j]*u[n][j]*v[n][j]) -------------
__global__ __launch_bounds__(256) void att_v2(
    const float* __restrict__ UVT, const float* __restrict__ Waw,
    const float* __restrict__ Wab, float* __restrict__ att, int N)
{
    int n = blockIdx.x * 256 + threadIdx.x;
    if (n >= N) return;
    const float* row = UVT + (long)n * 512;
    float s = Wab[0];
    for (int j = 0; j < 64; ++j) {
        float4 u4 = *(const float4*)(row + j * 4);
        float4 v4 = *(const float4*)(row + 256 + j * 4);
        float4 w4 = *(const float4*)(Waw + j * 4);
        s = fmaf(w4.x, u4.x * v4.x, s);
        s = fmaf(w4.y, u4.y * v4.y, s);
        s = fmaf(w4.z, u4.z * v4.z, s);
        s = fmaf(w4.w, u4.w * v4.w, s);
    }
    att[n] = 1.f / (1.f + expf(-s));
}

// ---------------- rank (stable descending) -> cluster id --------------------
__global__ __launch_bounds__(256) void rank_kernel(
    const float* __restrict__ att, int* __restrict__ cid, int N)
{
    __shared__ float sa[1024];
    int n = blockIdx.x * 256 + threadIdx.x;
    float a = (n < N) ? att[n] : 0.f;
    int r = 0;
    for (int base = 0; base < N; base += 1024) {
        int cnt = min(1024, N - base);
        for (int t = threadIdx.x; t < cnt; t += 256) sa[t] = att[base + t];
        __syncthreads();
        if (n < N) {
            for (int t = 0; t < cnt; ++t) {
                float aj = sa[t];
                int j = base + t;
                r += (int)(aj > a) | ((int)(aj == a) & (int)(j < n));
            }
        }
        __syncthreads();
    }
    if (n < N) cid[n] = (r * 10) / N;
}

// ---------------- fc_raw[k][m] from Hfeat bf16 ------------------------------
__global__ __launch_bounds__(256) void fc_reduce2(
    const u16* __restrict__ Hfeat, const float* __restrict__ att,
    const int* __restrict__ cid, float* __restrict__ fc_raw, int N)
{
    int m = blockIdx.x;
    float acc[10];
#pragma unroll
    for (int k = 0; k < 10; ++k) acc[k] = 0.f;
    for (int n = threadIdx.x; n < N; n += 256) {
        float hw = bf2f(Hfeat[(long)n * 512 + m]) * att[n];
        int c = cid[n];
#pragma unroll
        for (int k = 0; k < 10; ++k) acc[k] += (c == k) ? hw : 0.f;
    }
    __shared__ float red[256];
#pragma unroll
    for (int k = 0; k < 10; ++k) {
        red[threadIdx.x] = acc[k];
        __syncthreads();
        for (int s = 128; s > 0; s >>= 1) {
            if (threadIdx.x < s) red[threadIdx.x] += red[threadIdx.x + s];
            __syncthreads();
        }
        if (threadIdx.x == 0) fc_raw[k * 512 + m] = red[0];
        __syncthreads();
    }
}

// ---------------- sw[k], pc_raw[k][4] ---------------------------------------
__device__ __forceinline__ void anchor_coords(int n, float& cx, float& cy,
                                              float& bw, float& bh)
{
    int kh, kw, Wa, loc;
    if (n < 3721)       { kh = 3; kw = 3; Wa = 61; loc = n; }
    else if (n < 7690)  { kh = 1; kw = 1; Wa = 63; loc = n - 3721; }
    else if (n < 11533) { kh = 3; kw = 1; Wa = 63; loc = n - 7690; }
    else                { kh = 1; kw = 3; Wa = 61; loc = n - 11533; }
    int iy = loc / Wa, ix = loc - iy * Wa;
    cx = (ix + kw * 0.5f) * (1.f / 63.f);
    cy = (iy + kh * 0.5f) * (1.f / 63.f);
    bw = kw * (1.f / 63.f);
    bh = kh * (1.f / 63.f);
}

__global__ __launch_bounds__(256) void swpc_kernel(
    const float* __restrict__ att, const int* __restrict__ cid,
    float* __restrict__ sw, float* __restrict__ pc_raw, int N)
{
    float asw[10], ax[10], ay[10], aw[10], ah[10];
#pragma unroll
    for (int k = 0; k < 10; ++k) { asw[k] = ax[k] = ay[k] = aw[k] = ah[k] = 0.f; }
    for (int n = threadIdx.x; n < N; n += 256) {
        float a = att[n];
        int c = cid[n];
        float cx, cy, bw, bh;
        anchor_coords(n, cx, cy, bw, bh);
#pragma unroll
        for (int k = 0; k < 10; ++k) {
            float sel = (c == k) ? a : 0.f;
            asw[k] += sel;
            ax[k] = fmaf(sel, cx, ax[k]);
            ay[k] = fmaf(sel, cy, ay[k]);
            aw[k] = fmaf(sel, bw, aw[k]);
            ah[k] = fmaf(sel, bh, ah[k]);
        }
    }
    __shared__ float red[256];
#define RED_STORE(val, dst)                                                    \
    {                                                                          \
        red[threadIdx.x] = (val);                                              \
        __syncthreads();                                                       \
        for (int s = 128; s > 0; s >>= 1) {                                    \
            if (threadIdx.x < s) red[threadIdx.x] += red[threadIdx.x + s];     \
            __syncthreads();                                                   \
        }                                                                      \
        if (threadIdx.x == 0) (dst) = red[0];                                  \
        __syncthreads();                                                       \
    }
#pragma unroll
    for (int k = 0; k < 10; ++k) {
        RED_STORE(asw[k], sw[k]);
        RED_STORE(ax[k], pc_raw[k * 4 + 0]);
        RED_STORE(ay[k], pc_raw[k * 4 + 1]);
        RED_STORE(aw[k], pc_raw[k * 4 + 2]);
        RED_STORE(ah[k], pc_raw[k * 4 + 3]);
    }
#undef RED_STORE
}

// ---------------- head ------------------------------------------------------
__global__ __launch_bounds__(512) void final_kernel(
    const float* __restrict__ fc_raw, const float* __restrict__ sw,
    const float* __restrict__ pc_raw, const float* __restrict__ cluster_w,
    const float* __restrict__ cluster_b, const float* __restrict__ cls_w,
    const float* __restrict__ cls_b, float* __restrict__ out)
{
    __shared__ float red[512];
    int t = threadIdx.x;
    float fcn[10];
#pragma unroll
    for (int k = 0; k < 10; ++k)
        fcn[k] = fc_raw[k * 512 + t] / (sw[k] + 1e-8f);
    float cw = cluster_w[t];
    float sc[10];
#pragma unroll
    for (int k = 0; k < 10; ++k) {
        red[t] = fcn[k] * cw;
        __syncthreads();
        for (int s = 256; s > 0; s >>= 1) {
            if (t < s) red[t] += red[t + s];
            __syncthreads();
        }
        sc[k] = red[0] + cluster_b[0];
        __syncthreads();
    }
    float mx = sc[0];
#pragma unroll
    for (int k = 1; k < 10; ++k) mx = fmaxf(mx, sc[k]);
    float se = 0.f;
#pragma unroll
    for (int k = 0; k < 10; ++k) { sc[k] = expf(sc[k] - mx); se += sc[k]; }
    float inv = 1.f / se;
#pragma unroll
    for (int k = 0; k < 10; ++k) sc[k] *= inv;
    float fm = 0.f;
#pragma unroll
    for (int k = 0; k < 10; ++k) fm = fmaf(sc[k], fcn[k], fm);
    float lg[10];
#pragma unroll
    for (int c = 0; c < 10; ++c) {
        red[t] = fm * cls_w[c * 512 + t];
        __syncthreads();
        for (int s = 256; s > 0; s >>= 1) {
            if (t < s) red[t] += red[t + s];
            __syncthreads();
        }
        lg[c] = red[0] + cls_b[c];
        __syncthreads();
    }
    float mx2 = lg[0];
#pragma unroll
    for (int c = 1; c < 10; ++c) mx2 = fmaxf(mx2, lg[c]);
    float se2 = 0.f;
#pragma unroll
    for (int c = 0; c < 10; ++c) { lg[c] = expf(lg[c] - mx2); se2 += lg[c]; }
    float inv2 = 1.f / se2;
    if (t < 10) out[t] = lg[t] * inv2;
    if (t >= 10 && t < 20) out[t] = sc[t - 10];
    if (t >= 20 && t < 60) {
        int i = t - 20;
        out[t] = pc_raw[i] / (sw[i >> 2] + 1e-8f);
    }
}

// ---------------------------------------------------------------------------
extern "C" void kernel_launch(void* const* d_in, const int* in_sizes, int n_in,
                              void* d_out, int out_size, void* d_ws, size_t ws_size,
                              hipStream_t stream)
{
    const float* x    = (const float*)d_in[0];
    const float* c1w  = (const float*)d_in[1];   const float* c1b = (const float*)d_in[2];
    const float* c2w  = (const float*)d_in[3];   const float* c2b = (const float*)d_in[4];
    const float* c3w  = (const float*)d_in[5];   const float* c3b = (const float*)d_in[6];
    const float* a0w  = (const float*)d_in[7];   const float* a0b = (const float*)d_in[8];
    const float* a1w  = (const float*)d_in[9];   const float* a1b = (const float*)d_in[10];
    const float* a2w  = (const float*)d_in[11];  const float* a2b = (const float*)d_in[12];
    const float* a3w  = (const float*)d_in[13];  const float* a3b = (const float*)d_in[14];
    const float* W1w  = (const float*)d_in[15];  const float* W1b = (const float*)d_in[16];
    const float* Uw   = (const float*)d_in[17];  const float* Ub  = (const float*)d_in[18];
    const float* Vw   = (const float*)d_in[19];  const float* Vb  = (const float*)d_in[20];
    const float* Waw  = (const float*)d_in[21];  const float* Wab = (const float*)d_in[22];
    const float* clw  = (const float*)d_in[23];  const float* clb = (const float*)d_in[24];
    const float* clsw = (const float*)d_in[25];  const float* clsb= (const float*)d_in[26];
    float* out = (float*)d_out;

    // ---- workspace layout (float units), lifetime overlays ---------------
    // R0: h1T (conv1 out, dead after conv2) / Afeat (anchors out)
    // R2: h2T+h3T (dead after anchors)      / UVT (UV out)
    float* ws = (float*)d_ws;
    u16*   Afeat= (u16*)ws;                     // 15376*1024 u16
    u16*   h1T  = (u16*)ws;                     // 65025*128 u16 (overlay)
    u16*   Hfeat= (u16*)(ws + 7872512);         // 15376*512 u16
    float* UVT  = ws + 11808768;                // 15376*512 f32
    u16*   h2T  = (u16*)(ws + 11808768);        // 16129*256 u16 (overlay)
    u16*   h3T  = (u16*)(ws + 13873280);        // 4225*512 u16  (overlay)
    u16*   Wpk  = (u16*)(ws + 19681280);        // anchors packed, 8,388,608 u16
    u16*   W1pk = (u16*)(ws + 23875584);        // 512*1024
    u16*   UVpk = (u16*)(ws + 24137728);        // 512*512
    u16*   Wc2pk= (u16*)(ws + 24268800);        // 256*1152
    u16*   Wc3pk= (u16*)(ws + 24416256);        // 512*2304
    float* att  = ws + 25006080;                // 15,376
    int*   cid  = (int*)(ws + 25021456);        // 15,376
    float* fcr  = ws + 25036832;                // 5,120
    float* sw   = ws + 25041952;                // 10
    float* pcr  = ws + 25041962;                // 40
    // total ~25.04M floats ~= 100.2 MB

    u16* Wpk0 = Wpk;                 // a0: [1024][9*512]
    u16* Wpk1 = Wpk + 4718592;       // a1: [1024][512]
    u16* Wpk2 = Wpk + 5242880;       // a2: [1024][3*512]
    u16* Wpk3 = Wpk + 6815744;       // a3: [1024][3*512]

    dim3 blk(256);

    // ---- weight packing / casts ------------------------------------------
    pack_w<<<dim3(18432), blk, 0, stream>>>(a0w, Wpk0, 512, 9, 4718592L);
    pack_w<<<dim3(2048),  blk, 0, stream>>>(a1w, Wpk1, 512, 1, 524288L);
    pack_w<<<dim3(6144),  blk, 0, stream>>>(a2w, Wpk2, 512, 3, 1572864L);
    pack_w<<<dim3(6144),  blk, 0, stream>>>(a3w, Wpk3, 512, 3, 1572864L);
    pack_w<<<dim3(1152),  blk, 0, stream>>>(c2w, Wc2pk, 128, 9, 294912L);
    pack_w<<<dim3(4608),  blk, 0, stream>>>(c3w, Wc3pk, 256, 9, 1179648L);
    cast_bf<<<dim3(2048), blk, 0, stream>>>(W1w, W1pk, 524288L);
    cast_bf<<<dim3(512),  blk, 0, stream>>>(Uw, UVpk, 131072L);
    cast_bf<<<dim3(512),  blk, 0, stream>>>(Vw, UVpk + 131072, 131072L);

    // ---- backbone --------------------------------------------------------
    conv1k<<<dim3(255, 8), blk, 0, stream>>>(x, c1w, c1b, h1T);
    // conv2: M=256, N=127*127=16129, K=9*128=1152 -> h2T[sp][256] bf16
    gemm_bt<2,4,5><<<dim3(127, 2), blk, 0, stream>>>(Wc2pk, h1T, c2b, nullptr, h2T, 256, 16129, 128, 18, 0, 0, 0);
    // conv3: M=512, N=63*63=3969, K=9*256=2304 -> h3T padded scatter
    gemm_bt<3,3,6><<<dim3(32, 4),  blk, 0, stream>>>(Wc3pk, h2T, c3b, nullptr, h3T, 512, 3969, 256, 36, 0, 0, 0);

    // ---- anchor GEMMs -> Afeat[n][1024] bf16 -----------------------------
    gemm_bt<0,0,0><<<dim3(32, 8), blk, 0, stream>>>(Wpk0, h3T, a0b, nullptr, Afeat, 1024, 3969, 512, 72, 61, 61, 0);
    gemm_bt<0,0,1><<<dim3(32, 8), blk, 0, stream>>>(Wpk1, h3T, a1b, nullptr, Afeat, 1024, 3969, 512, 8,  63, 63, 3721);
    gemm_bt<0,0,2><<<dim3(32, 8), blk, 0, stream>>>(Wpk2, h3T, a2b, nullptr, Afeat, 1024, 3969, 512, 24, 61, 63, 7690);
    gemm_bt<0,0,3><<<dim3(32, 8), blk, 0, stream>>>(Wpk3, h3T, a3b, nullptr, Afeat, 1024, 3969, 512, 24, 63, 61, 11533);

    // ---- W1 GEMM: Hfeat[n][512] = relu(W1 @ feat + b), bf16 --------------
    gemm_bt<1,1,4><<<dim3(121, 4), blk, 0, stream>>>(W1pk, Afeat, W1b, nullptr, Hfeat, 512, NTOT, 1024, 16, 0, 0, 0);

    // ---- UV GEMM: UVT[n][512] = {sigmoid(U h), tanh(V h)}, fp32 ----------
    gemm_bt<1,2,1><<<dim3(121, 4), blk, 0, stream>>>(UVpk, Hfeat, Ub, Vb, UVT, 512, NTOT, 512, 8, 0, 0, 0);

    // ---- attention, rank, reductions, head -------------------------------
    att_v2<<<dim3(61), blk, 0, stream>>>(UVT, Waw, Wab, att, NTOT);
    rank_kernel<<<dim3(61), blk, 0, stream>>>(att, cid, NTOT);
    fc_reduce2<<<dim3(512), blk, 0, stream>>>(Hfeat, att, cid, fcr, NTOT);
    swpc_kernel<<<dim3(1), blk, 0, stream>>>(att, cid, sw, pcr, NTOT);
    final_kernel<<<dim3(1), dim3(512), 0, stream>>>(fcr, sw, pcr, clw, clb, clsw, clsb, out);
}

// Round 4
// 916.386 us; speedup vs baseline: 5.9483x; 1.3711x over previous
//
#include <hip/hip_runtime.h>
#include <math.h>

// ---------------------------------------------------------------------------
// Round 3: tail fixes. rank O(N^2) chunk-parallel (412us -> ~8us expected),
// fc_reduce and swpc restructured into deterministic two-stage partials.
// GEMM engine unchanged from round 2.
// ---------------------------------------------------------------------------

#define NTOT 15376
typedef unsigned short u16;
typedef unsigned long long u64;
typedef __attribute__((ext_vector_type(8))) short bf16x8;
typedef __attribute__((ext_vector_type(4))) float f32x4;

static __device__ __forceinline__ u16 f2bf(float x) {
    union { float f; unsigned u; } v; v.f = x;
    unsigned r = v.u + 0x7FFF + ((v.u >> 16) & 1);
    return (u16)(r >> 16);
}
static __device__ __forceinline__ float bf2f(u16 h) {
    union { unsigned u; float f; } v; v.u = ((unsigned)h) << 16;
    return v.f;
}

// ---------------- conv1: fp32 direct, OCB=16, bf16 transposed output --------
__global__ __launch_bounds__(256) void conv1k(
    const float* __restrict__ in, const float* __restrict__ wt,
    const float* __restrict__ bs, u16* __restrict__ h1T)
{
    int sp = blockIdx.x * 256 + threadIdx.x;
    if (sp >= 255 * 255) return;
    int oc0 = blockIdx.y * 16;
    int oy = sp / 255, ox = sp - oy * 255;
    const float* ip = in + (long)oy * 2 * 512 + ox * 2;
    float acc[16];
#pragma unroll
    for (int o = 0; o < 16; ++o) acc[o] = bs[oc0 + o];
#pragma unroll
    for (int ic = 0; ic < 3; ++ic)
#pragma unroll
        for (int ky = 0; ky < 3; ++ky)
#pragma unroll
            for (int kx = 0; kx < 3; ++kx) {
                float x = ip[ic * 262144 + ky * 512 + kx];
                const float* wp = wt + oc0 * 27 + ic * 9 + ky * 3 + kx;
#pragma unroll
                for (int o = 0; o < 16; ++o)
                    acc[o] = fmaf(x, wp[o * 27], acc[o]);
            }
    u16* dst = h1T + (long)sp * 128 + oc0;
#pragma unroll
    for (int g = 0; g < 4; ++g) {
        u64 pk = (u64)f2bf(acc[g * 4 + 0])
               | ((u64)f2bf(acc[g * 4 + 1]) << 16)
               | ((u64)f2bf(acc[g * 4 + 2]) << 32)
               | ((u64)f2bf(acc[g * 4 + 3]) << 48);
        *(u64*)(dst + g * 4) = pk;
    }
}

// ---------------- weight packing -------------------------------------------
__global__ __launch_bounds__(256) void pack_w(
    const float* __restrict__ src, u16* __restrict__ dst, int IC, int NT, long total)
{
    long i = (long)blockIdx.x * 256 + threadIdx.x;
    if (i >= total) return;
    int ic = (int)(i % IC);
    long r = i / IC;
    int t = (int)(r % NT);
    long oc = r / NT;
    dst[i] = f2bf(src[(oc * IC + ic) * NT + t]);
}

__global__ __launch_bounds__(256) void cast_bf(
    const float* __restrict__ src, u16* __restrict__ dst, long total)
{
    long i = (long)blockIdx.x * 256 + threadIdx.x;
    if (i < total) dst[i] = f2bf(src[i]);
}

// ---------------- the MFMA BT-GEMM (unchanged from round 2) -----------------
template<int CMODE, int EMODE, int TMODE>
__global__ __launch_bounds__(256) void gemm_bt(
    const u16* __restrict__ A, const u16* __restrict__ B,
    const float* __restrict__ bias0, const float* __restrict__ bias1,
    void* __restrict__ Cout, int M, int N, int RSB, int Ktot,
    int OH, int OW, int obase)
{
    __shared__ u16 As[8192];
    __shared__ u16 Bs[8192];
    const int tid = threadIdx.x, w = tid >> 6, l = tid & 63;
    const int wr = w >> 1, wc = w & 1;
    const int n0 = blockIdx.x * 128, m0 = blockIdx.y * 128;
    const long RSA = (long)Ktot * 64;
    const int sl = l & 7, sh = l >> 3;
    constexpr int ICL2 = (TMODE == 5) ? 1 : (TMODE == 6) ? 2 : 3;
    constexpr int KBM  = (1 << ICL2) - 1;

    int offB[4], wOff[4];
    long aRow[4];
#pragma unroll
    for (int j = 0; j < 4; ++j) {
        int r = w * 32 + j * 8 + sh;
        int gn = n0 + r;
        if (CMODE == 0)      { gn = min(gn, 3968);  offB[j] = (gn / 63) * 65 + (gn % 63); }
        else if (CMODE == 1) { offB[j] = min(gn, N - 1); }
        else if (CMODE == 2) { gn = min(gn, 16128); offB[j] = (gn / 127) * 510 + (gn % 127) * 2; }
        else                 { gn = min(gn, 3968);  offB[j] = (gn / 63) * 254 + (gn % 63) * 2; }
        wOff[j] = r * 128 + ((sl ^ sh) * 16);
        aRow[j] = ((long)(m0 + r) * RSA + sl * 8) * 2;
    }

    f32x4 acc[4][4];
#pragma unroll
    for (int a = 0; a < 4; ++a)
#pragma unroll
        for (int b = 0; b < 4; ++b) acc[a][b] = (f32x4){0.f, 0.f, 0.f, 0.f};

    uint4 ra[4], rb[4];
#define GLOAD(kt)                                                              \
    {                                                                          \
        int t_ = (kt) >> ICL2, kb_ = (kt) & KBM;                               \
        int trow_ = 0, tcol_ = 0;                                              \
        if (TMODE == 0)      { trow_ = (t_ / 3) * 65 + (t_ % 3); }             \
        else if (TMODE == 2) { trow_ = t_ * 65; }                              \
        else if (TMODE == 3) { trow_ = t_; }                                   \
        else if (TMODE == 4) { tcol_ = t_ * 512; }                             \
        else if (TMODE == 5) { trow_ = (t_ / 3) * 255 + (t_ % 3); }            \
        else if (TMODE == 6) { trow_ = (t_ / 3) * 127 + (t_ % 3); }            \
        long cbA_ = (long)(kt) * 128;                                          \
        long cbB_ = ((long)tcol_ + kb_ * 64 + sl * 8) * 2;                     \
        _Pragma("unroll")                                                      \
        for (int j = 0; j < 4; ++j) {                                          \
            ra[j] = *(const uint4*)((const char*)A + aRow[j] + cbA_);          \
            rb[j] = *(const uint4*)((const char*)B +                           \
                        (long)(offB[j] + trow_) * RSB * 2 + cbB_);             \
        }                                                                      \
    }

    GLOAD(0);
    for (int kt = 0; kt < Ktot; ++kt) {
        __syncthreads();
#pragma unroll
        for (int j = 0; j < 4; ++j) {
            *(uint4*)((char*)As + wOff[j]) = ra[j];
            *(uint4*)((char*)Bs + wOff[j]) = rb[j];
        }
        __syncthreads();
        if (kt + 1 < Ktot) GLOAD(kt + 1);
#pragma unroll
        for (int kk = 0; kk < 2; ++kk) {
            bf16x8 af[4], bfr[4];
#pragma unroll
            for (int f = 0; f < 4; ++f) {
                int rm = wr * 64 + f * 16 + (l & 15);
                af[f] = *(const bf16x8*)((const char*)As + rm * 128 +
                           (((kk * 4 + (l >> 4)) ^ (rm & 7)) * 16));
                int rn = wc * 64 + f * 16 + (l & 15);
                bfr[f] = *(const bf16x8*)((const char*)Bs + rn * 128 +
                           (((kk * 4 + (l >> 4)) ^ (rn & 7)) * 16));
            }
#pragma unroll
            for (int fm = 0; fm < 4; ++fm)
#pragma unroll
                for (int fn = 0; fn < 4; ++fn)
                    acc[fm][fn] = __builtin_amdgcn_mfma_f32_16x16x32_bf16(
                        af[fm], bfr[fn], acc[fm][fn], 0, 0, 0);
        }
    }
#undef GLOAD

#pragma unroll
    for (int fm = 0; fm < 4; ++fm) {
        int gmb = m0 + wr * 64 + fm * 16 + (l >> 4) * 4;
#pragma unroll
        for (int fn = 0; fn < 4; ++fn) {
            int gn = n0 + wc * 64 + fn * 16 + (l & 15);
            f32x4 v = acc[fm][fn];
            if (EMODE == 0) {
                if (gn < 3969) {
                    int oy = gn / 63, ox = gn - oy * 63;
                    if (oy < OH && ox < OW) {
                        int trg = obase + oy * OW + ox;
                        float4 bv = *(const float4*)(bias0 + gmb);
                        u64 pk = (u64)f2bf(v.x + bv.x)
                               | ((u64)f2bf(v.y + bv.y) << 16)
                               | ((u64)f2bf(v.z + bv.z) << 32)
                               | ((u64)f2bf(v.w + bv.w) << 48);
                        *(u64*)((u16*)Cout + (long)trg * M + gmb) = pk;
                    }
                }
            } else if (EMODE == 1) {
                if (gn < N) {
                    float4 bv = *(const float4*)(bias0 + gmb);
                    u64 pk = (u64)f2bf(fmaxf(v.x + bv.x, 0.f))
                           | ((u64)f2bf(fmaxf(v.y + bv.y, 0.f)) << 16)
                           | ((u64)f2bf(fmaxf(v.z + bv.z, 0.f)) << 32)
                           | ((u64)f2bf(fmaxf(v.w + bv.w, 0.f)) << 48);
                    *(u64*)((u16*)Cout + (long)gn * M + gmb) = pk;
                }
            } else if (EMODE == 2) {
                if (gn < N) {
                    float4 o;
                    if (gmb < 256) {
                        float4 bv = *(const float4*)(bias0 + gmb);
                        o.x = 1.f / (1.f + expf(-(v.x + bv.x)));
                        o.y = 1.f / (1.f + expf(-(v.y + bv.y)));
                        o.z = 1.f / (1.f + expf(-(v.z + bv.z)));
                        o.w = 1.f / (1.f + expf(-(v.w + bv.w)));
                    } else {
                        float4 bv = *(const float4*)(bias1 + gmb - 256);
                        o.x = tanhf(v.x + bv.x); o.y = tanhf(v.y + bv.y);
                        o.z = tanhf(v.z + bv.z); o.w = tanhf(v.w + bv.w);
                    }
                    *(float4*)((float*)Cout + (long)gn * M + gmb) = o;
                }
            } else if (EMODE == 3) {
                if (gn < 3969) {
                    int trg = (gn / 63) * 65 + (gn % 63);
                    float4 bv = *(const float4*)(bias0 + gmb);
                    u64 pk = (u64)f2bf(v.x + bv.x)
                           | ((u64)f2bf(v.y + bv.y) << 16)
                           | ((u64)f2bf(v.z + bv.z) << 32)
                           | ((u64)f2bf(v.w + bv.w) << 48);
                    *(u64*)((u16*)Cout + (long)trg * M + gmb) = pk;
                }
            } else {
                if (gn < N) {
                    float4 bv = *(const float4*)(bias0 + gmb);
                    u64 pk = (u64)f2bf(v.x + bv.x)
                           | ((u64)f2bf(v.y + bv.y) << 16)
                           | ((u64)f2bf(v.z + bv.z) << 32)
                           | ((u64)f2bf(v.w + bv.w) << 48);
                    *(u64*)((u16*)Cout + (long)gn * M + gmb) = pk;
                }
            }
        }
    }
}

// ---------------- att[n] = sigmoid(sum_j Wa[j]*u[n][j]*v[n][j]) -------------
__global__ __launch_bounds__(256) void att_v2(
    const float* __restrict__ UVT, const float* __restrict__ Waw,
    const float* __restrict__ Wab, float* __restrict__ att, int N)
{
    int n = blockIdx.x * 256 + threadIdx.x;
    if (n >= N) return;
    const float* row = UVT + (long)n * 512;
    float s = Wab[0];
    for (int j = 0; j < 64; ++j) {
        float4 u4 = *(const float4*)(row + j * 4);
        float4 v4 = *(const float4*)(row + 256 + j * 4);
        float4 w4 = *(const float4*)(Waw + j * 4);
        s = fmaf(w4.x, u4.x * v4.x, s);
        s = fmaf(w4.y, u4.y * v4.y, s);
        s = fmaf(w4.z, u4.z * v4.z, s);
        s = fmaf(w4.w, u4.w * v4.w, s);
    }
    att[n] = 1.f / (1.f + expf(-s));
}

// ---------------- rank: chunk-parallel partial counts -----------------------
__global__ __launch_bounds__(256) void zero_int(int* __restrict__ p, int n)
{
    int i = blockIdx.x * 256 + threadIdx.x;
    if (i < n) p[i] = 0;
}

__global__ __launch_bounds__(256) void rank_partial(
    const float* __restrict__ att, int* __restrict__ rank, int N)
{
    __shared__ float sa[1024];
    int n = blockIdx.x * 256 + threadIdx.x;
    int base = blockIdx.y * 1024;
    int cnt = min(1024, N - base);
    for (int t = threadIdx.x; t < cnt; t += 256) sa[t] = att[base + t];
    __syncthreads();
    if (n >= N) return;
    float a = att[n];
    int r = 0;
    for (int t = 0; t < cnt; ++t) {
        float aj = sa[t];
        int j = base + t;
        r += (int)(aj > a) | ((int)(aj == a) & (int)(j < n));
    }
    atomicAdd(&rank[n], r);
}

__global__ __launch_bounds__(256) void cid_from_rank(
    const int* __restrict__ rank, int* __restrict__ cid, int N)
{
    int n = blockIdx.x * 256 + threadIdx.x;
    if (n < N) cid[n] = (rank[n] * 10) / N;
}

// ---------------- fc partials: register accumulators, coalesced reads -------
#define FC_NB 64
#define FC_CHUNK 241   // 64*241 = 15424 >= 15376
__global__ __launch_bounds__(256) void fc_part(
    const u16* __restrict__ Hfeat, const float* __restrict__ att,
    const int* __restrict__ cid, float* __restrict__ fcp, int N)
{
    int t = threadIdx.x, b = blockIdx.x;
    float acc0[10], acc1[10];
#pragma unroll
    for (int k = 0; k < 10; ++k) { acc0[k] = 0.f; acc1[k] = 0.f; }
    int n0 = b * FC_CHUNK, n1 = min(N, n0 + FC_CHUNK);
    for (int n = n0; n < n1; ++n) {
        float a = att[n];
        int c = cid[n];
        float h0 = bf2f(Hfeat[(long)n * 512 + t]) * a;
        float h1 = bf2f(Hfeat[(long)n * 512 + t + 256]) * a;
#pragma unroll
        for (int k = 0; k < 10; ++k) {
            acc0[k] += (c == k) ? h0 : 0.f;
            acc1[k] += (c == k) ? h1 : 0.f;
        }
    }
    float* dst = fcp + (long)b * 5120;
#pragma unroll
    for (int k = 0; k < 10; ++k) {
        dst[k * 512 + t]       = acc0[k];
        dst[k * 512 + t + 256] = acc1[k];
    }
}

// fc_raw[i] = sum_b fcp[b][i], fixed order (deterministic)
__global__ __launch_bounds__(256) void fc_sum(
    const float* __restrict__ fcp, float* __restrict__ fc_raw)
{
    int i = blockIdx.x * 256 + threadIdx.x;
    if (i >= 5120) return;
    float s = 0.f;
    for (int b = 0; b < FC_NB; ++b) s += fcp[(long)b * 5120 + i];
    fc_raw[i] = s;
}

// ---------------- sw/pc partials: wave shfl reduce ---------------------------
__device__ __forceinline__ void anchor_coords(int n, float& cx, float& cy,
                                              float& bw, float& bh)
{
    int kh, kw, Wa, loc;
    if (n < 3721)       { kh = 3; kw = 3; Wa = 61; loc = n; }
    else if (n < 7690)  { kh = 1; kw = 1; Wa = 63; loc = n - 3721; }
    else if (n < 11533) { kh = 3; kw = 1; Wa = 63; loc = n - 7690; }
    else                { kh = 1; kw = 3; Wa = 61; loc = n - 11533; }
    int iy = loc / Wa, ix = loc - iy * Wa;
    cx = (ix + kw * 0.5f) * (1.f / 63.f);
    cy = (iy + kh * 0.5f) * (1.f / 63.f);
    bw = kw * (1.f / 63.f);
    bh = kh * (1.f / 63.f);
}

// prt[b][k*5+d]: d=0 sw, d=1..4 pc(x,y,w,h)
__global__ __launch_bounds__(256) void swpc_part(
    const float* __restrict__ att, const int* __restrict__ cid,
    float* __restrict__ prt, int N)
{
    __shared__ float red[4][50];
    int t = threadIdx.x, b = blockIdx.x;
    int n = b * 256 + t;
    int l = t & 63, w = t >> 6;
    float a = 0.f, cx = 0.f, cy = 0.f, bw = 0.f, bh = 0.f;
    int c = -1;
    if (n < N) { a = att[n]; c = cid[n]; anchor_coords(n, cx, cy, bw, bh); }
#pragma unroll
    for (int k = 0; k < 10; ++k) {
        float sel = (c == k) ? a : 0.f;
        float v[5] = {sel, sel * cx, sel * cy, sel * bw, sel * bh};
#pragma unroll
        for (int d = 0; d < 5; ++d) {
            float x = v[d];
#pragma unroll
            for (int s = 1; s < 64; s <<= 1) x += __shfl_xor(x, s, 64);
            if (l == 0) red[w][k * 5 + d] = x;
        }
    }
    __syncthreads();
    if (t < 50) prt[b * 50 + t] = red[0][t] + red[1][t] + red[2][t] + red[3][t];
}

__global__ __launch_bounds__(64) void swpc_sum(
    const float* __restrict__ prt, float* __restrict__ sw,
    float* __restrict__ pcr, int NB)
{
    int j = threadIdx.x;
    if (j >= 50) return;
    float s = 0.f;
    for (int b = 0; b < NB; ++b) s += prt[b * 50 + j];
    int k = j / 5, d = j % 5;
    if (d == 0) sw[k] = s;
    else        pcr[k * 4 + (d - 1)] = s;
}

// ---------------- head ------------------------------------------------------
__global__ __launch_bounds__(512) void final_kernel(
    const float* __restrict__ fc_raw, const float* __restrict__ sw,
    const float* __restrict__ pc_raw, const float* __restrict__ cluster_w,
    const float* __restrict__ cluster_b, const float* __restrict__ cls_w,
    const float* __restrict__ cls_b, float* __restrict__ out)
{
    __shared__ float red[512];
    int t = threadIdx.x;
    float fcn[10];
#pragma unroll
    for (int k = 0; k < 10; ++k)
        fcn[k] = fc_raw[k * 512 + t] / (sw[k] + 1e-8f);
    float cw = cluster_w[t];
    float sc[10];
#pragma unroll
    for (int k = 0; k < 10; ++k) {
        red[t] = fcn[k] * cw;
        __syncthreads();
        for (int s = 256; s > 0; s >>= 1) {
            if (t < s) red[t] += red[t + s];
            __syncthreads();
        }
        sc[k] = red[0] + cluster_b[0];
        __syncthreads();
    }
    float mx = sc[0];
#pragma unroll
    for (int k = 1; k < 10; ++k) mx = fmaxf(mx, sc[k]);
    float se = 0.f;
#pragma unroll
    for (int k = 0; k < 10; ++k) { sc[k] = expf(sc[k] - mx); se += sc[k]; }
    float inv = 1.f / se;
#pragma unroll
    for (int k = 0; k < 10; ++k) sc[k] *= inv;
    float fm = 0.f;
#pragma unroll
    for (int k = 0; k < 10; ++k) fm = fmaf(sc[k], fcn[k], fm);
    float lg[10];
#pragma unroll
    for (int c = 0; c < 10; ++c) {
        red[t] = fm * cls_w[c * 512 + t];
        __syncthreads();
        for (int s = 256; s > 0; s >>= 1) {
            if (t < s) red[t] += red[t + s];
            __syncthreads();
        }
        lg[c] = red[0] + cls_b[c];
        __syncthreads();
    }
    float mx2 = lg[0];
#pragma unroll
    for (int c = 1; c < 10; ++c) mx2 = fmaxf(mx2, lg[c]);
    float se2 = 0.f;
#pragma unroll
    for (int c = 0; c < 10; ++c) { lg[c] = expf(lg[c] - mx2); se2 += lg[c]; }
    float inv2 = 1.f / se2;
    if (t < 10) out[t] = lg[t] * inv2;
    if (t >= 10 && t < 20) out[t] = sc[t - 10];
    if (t >= 20 && t < 60) {
        int i = t - 20;
        out[t] = pc_raw[i] / (sw[i >> 2] + 1e-8f);
    }
}

// ---------------------------------------------------------------------------
extern "C" void kernel_launch(void* const* d_in, const int* in_sizes, int n_in,
                              void* d_out, int out_size, void* d_ws, size_t ws_size,
                              hipStream_t stream)
{
    const float* x    = (const float*)d_in[0];
    const float* c1w  = (const float*)d_in[1];   const float* c1b = (const float*)d_in[2];
    const float* c2w  = (const float*)d_in[3];   const float* c2b = (const float*)d_in[4];
    const float* c3w  = (const float*)d_in[5];   const float* c3b = (const float*)d_in[6];
    const float* a0w  = (const float*)d_in[7];   const float* a0b = (const float*)d_in[8];
    const float* a1w  = (const float*)d_in[9];   const float* a1b = (const float*)d_in[10];
    const float* a2w  = (const float*)d_in[11];  const float* a2b = (const float*)d_in[12];
    const float* a3w  = (const float*)d_in[13];  const float* a3b = (const float*)d_in[14];
    const float* W1w  = (const float*)d_in[15];  const float* W1b = (const float*)d_in[16];
    const float* Uw   = (const float*)d_in[17];  const float* Ub  = (const float*)d_in[18];
    const float* Vw   = (const float*)d_in[19];  const float* Vb  = (const float*)d_in[20];
    const float* Waw  = (const float*)d_in[21];  const float* Wab = (const float*)d_in[22];
    const float* clw  = (const float*)d_in[23];  const float* clb = (const float*)d_in[24];
    const float* clsw = (const float*)d_in[25];  const float* clsb= (const float*)d_in[26];
    float* out = (float*)d_out;

    // ---- workspace layout (float units), lifetime overlays ---------------
    float* ws = (float*)d_ws;
    u16*   Afeat= (u16*)ws;                     // 15376*1024 u16
    u16*   h1T  = (u16*)ws;                     // 65025*128 u16 (overlay)
    u16*   Hfeat= (u16*)(ws + 7872512);         // 15376*512 u16
    float* UVT  = ws + 11808768;                // 15376*512 f32
    u16*   h2T  = (u16*)(ws + 11808768);        // 16129*256 u16 (overlay)
    u16*   h3T  = (u16*)(ws + 13873280);        // 4225*512 u16  (overlay)
    u16*   Wpk  = (u16*)(ws + 19681280);        // anchors packed
    u16*   W1pk = (u16*)(ws + 23875584);
    u16*   UVpk = (u16*)(ws + 24137728);
    u16*   Wc2pk= (u16*)(ws + 24268800);
    u16*   Wc3pk= (u16*)(ws + 24416256);
    float* att  = ws + 25006080;                // 15,376
    int*   cid  = (int*)(ws + 25021456);        // 15,376
    int*   rank = (int*)(ws + 25036832);        // 15,376
    float* fcr  = ws + 25052208;                // 5,120
    float* sw   = ws + 25057328;                // 10
    float* pcr  = ws + 25057338;                // 40
    float* fcp  = ws + 25057378;                // 64*5120 = 327,680
    float* prt  = ws + 25385058;                // 61*50   = 3,050
    // total ~25.39M floats ~= 101.6 MB

    u16* Wpk0 = Wpk;
    u16* Wpk1 = Wpk + 4718592;
    u16* Wpk2 = Wpk + 5242880;
    u16* Wpk3 = Wpk + 6815744;

    dim3 blk(256);

    // ---- weight packing / casts ------------------------------------------
    pack_w<<<dim3(18432), blk, 0, stream>>>(a0w, Wpk0, 512, 9, 4718592L);
    pack_w<<<dim3(2048),  blk, 0, stream>>>(a1w, Wpk1, 512, 1, 524288L);
    pack_w<<<dim3(6144),  blk, 0, stream>>>(a2w, Wpk2, 512, 3, 1572864L);
    pack_w<<<dim3(6144),  blk, 0, stream>>>(a3w, Wpk3, 512, 3, 1572864L);
    pack_w<<<dim3(1152),  blk, 0, stream>>>(c2w, Wc2pk, 128, 9, 294912L);
    pack_w<<<dim3(4608),  blk, 0, stream>>>(c3w, Wc3pk, 256, 9, 1179648L);
    cast_bf<<<dim3(2048), blk, 0, stream>>>(W1w, W1pk, 524288L);
    cast_bf<<<dim3(512),  blk, 0, stream>>>(Uw, UVpk, 131072L);
    cast_bf<<<dim3(512),  blk, 0, stream>>>(Vw, UVpk + 131072, 131072L);

    // ---- backbone ----------------------------------------------------------
    conv1k<<<dim3(255, 8), blk, 0, stream>>>(x, c1w, c1b, h1T);
    gemm_bt<2,4,5><<<dim3(127, 2), blk, 0, stream>>>(Wc2pk, h1T, c2b, nullptr, h2T, 256, 16129, 128, 18, 0, 0, 0);
    gemm_bt<3,3,6><<<dim3(32, 4),  blk, 0, stream>>>(Wc3pk, h2T, c3b, nullptr, h3T, 512, 3969, 256, 36, 0, 0, 0);

    // ---- anchor GEMMs -> Afeat[n][1024] bf16 -------------------------------
    gemm_bt<0,0,0><<<dim3(32, 8), blk, 0, stream>>>(Wpk0, h3T, a0b, nullptr, Afeat, 1024, 3969, 512, 72, 61, 61, 0);
    gemm_bt<0,0,1><<<dim3(32, 8), blk, 0, stream>>>(Wpk1, h3T, a1b, nullptr, Afeat, 1024, 3969, 512, 8,  63, 63, 3721);
    gemm_bt<0,0,2><<<dim3(32, 8), blk, 0, stream>>>(Wpk2, h3T, a2b, nullptr, Afeat, 1024, 3969, 512, 24, 61, 63, 7690);
    gemm_bt<0,0,3><<<dim3(32, 8), blk, 0, stream>>>(Wpk3, h3T, a3b, nullptr, Afeat, 1024, 3969, 512, 24, 63, 61, 11533);

    // ---- W1 / UV GEMMs -----------------------------------------------------
    gemm_bt<1,1,4><<<dim3(121, 4), blk, 0, stream>>>(W1pk, Afeat, W1b, nullptr, Hfeat, 512, NTOT, 1024, 16, 0, 0, 0);
    gemm_bt<1,2,1><<<dim3(121, 4), blk, 0, stream>>>(UVpk, Hfeat, Ub, Vb, UVT, 512, NTOT, 512, 8, 0, 0, 0);

    // ---- attention, rank, reductions, head ---------------------------------
    att_v2<<<dim3(61), blk, 0, stream>>>(UVT, Waw, Wab, att, NTOT);
    zero_int<<<dim3(61), blk, 0, stream>>>(rank, NTOT);
    rank_partial<<<dim3(61, 16), blk, 0, stream>>>(att, rank, NTOT);
    cid_from_rank<<<dim3(61), blk, 0, stream>>>(rank, cid, NTOT);
    fc_part<<<dim3(FC_NB), blk, 0, stream>>>(Hfeat, att, cid, fcp, NTOT);
    fc_sum<<<dim3(20), blk, 0, stream>>>(fcp, fcr);
    swpc_part<<<dim3(61), blk, 0, stream>>>(att, cid, prt, NTOT);
    swpc_sum<<<dim3(1), dim3(64), 0, stream>>>(prt, sw, pcr, 61);
    final_kernel<<<dim3(1), dim3(512), 0, stream>>>(fcr, sw, pcr, clw, clb, clsw, clsb, out);
}

// Round 5
// 475.595 us; speedup vs baseline: 11.4613x; 1.9268x over previous
//
#include <hip/hip_runtime.h>
#include <math.h>

// ---------------------------------------------------------------------------
// Round 4: GEMM engine on global_load_lds (width 16, linear LDS dest +
// inverse-swizzled global source per rule 21), all 4 anchor GEMMs fused into
// one 1024-block dispatch, 9 weight-pack launches fused into 1.
// ---------------------------------------------------------------------------

#define NTOT 15376
typedef unsigned short u16;
typedef unsigned long long u64;
typedef __attribute__((ext_vector_type(8))) short bf16x8;
typedef __attribute__((ext_vector_type(4))) float f32x4;

static __device__ __forceinline__ u16 f2bf(float x) {
    union { float f; unsigned u; } v; v.f = x;
    unsigned r = v.u + 0x7FFF + ((v.u >> 16) & 1);
    return (u16)(r >> 16);
}
static __device__ __forceinline__ float bf2f(u16 h) {
    union { unsigned u; float f; } v; v.u = ((unsigned)h) << 16;
    return v.f;
}

// async global->LDS, 16B per lane; LDS dest = wave-uniform base + lane*16
static __device__ __forceinline__ void glds16(const void* g, void* l) {
    __builtin_amdgcn_global_load_lds(
        (const __attribute__((address_space(1))) void*)g,
        (__attribute__((address_space(3))) void*)l,
        16, 0, 0);
}

// ---------------- conv1: fp32 direct, OCB=16, bf16 transposed output --------
__global__ __launch_bounds__(256) void conv1k(
    const float* __restrict__ in, const float* __restrict__ wt,
    const float* __restrict__ bs, u16* __restrict__ h1T)
{
    int sp = blockIdx.x * 256 + threadIdx.x;
    if (sp >= 255 * 255) return;
    int oc0 = blockIdx.y * 16;
    int oy = sp / 255, ox = sp - oy * 255;
    const float* ip = in + (long)oy * 2 * 512 + ox * 2;
    float acc[16];
#pragma unroll
    for (int o = 0; o < 16; ++o) acc[o] = bs[oc0 + o];
#pragma unroll
    for (int ic = 0; ic < 3; ++ic)
#pragma unroll
        for (int ky = 0; ky < 3; ++ky)
#pragma unroll
            for (int kx = 0; kx < 3; ++kx) {
                float x = ip[ic * 262144 + ky * 512 + kx];
                const float* wp = wt + oc0 * 27 + ic * 9 + ky * 3 + kx;
#pragma unroll
                for (int o = 0; o < 16; ++o)
                    acc[o] = fmaf(x, wp[o * 27], acc[o]);
            }
    u16* dst = h1T + (long)sp * 128 + oc0;
#pragma unroll
    for (int g = 0; g < 4; ++g) {
        u64 pk = (u64)f2bf(acc[g * 4 + 0])
               | ((u64)f2bf(acc[g * 4 + 1]) << 16)
               | ((u64)f2bf(acc[g * 4 + 2]) << 32)
               | ((u64)f2bf(acc[g * 4 + 3]) << 48);
        *(u64*)(dst + g * 4) = pk;
    }
}

// ---------------- fused weight packing (all 9 jobs, contiguous dst) ---------
// dst[(oc*NT + t)*IC + ic] = src[(oc*IC+ic)*NT + t]
__global__ __launch_bounds__(256) void pack_all(
    const float* __restrict__ s0, const float* __restrict__ s1,
    const float* __restrict__ s2, const float* __restrict__ s3,
    const float* __restrict__ s4, const float* __restrict__ s5,
    const float* __restrict__ s6, const float* __restrict__ s7,
    const float* __restrict__ s8, u16* __restrict__ dst)
{
    long i = (long)blockIdx.x * 256 + threadIdx.x;
    if (i >= 10649600L) return;
    // job boundaries (cumulative element offsets in dst)
    const long c1 = 4718592L, c2 = 5242880L, c3 = 6815744L, c4 = 8388608L,
               c5 = 8912896L, c6 = 9043968L, c7 = 9175040L, c8 = 9469952L;
    const float* src; long base; int IC, NT;
    if      (i < c1) { src = s0; base = 0;  IC = 512;  NT = 9; }
    else if (i < c2) { src = s1; base = c1; IC = 512;  NT = 1; }
    else if (i < c3) { src = s2; base = c2; IC = 512;  NT = 3; }
    else if (i < c4) { src = s3; base = c3; IC = 512;  NT = 3; }
    else if (i < c5) { src = s4; base = c4; IC = 1024; NT = 1; }
    else if (i < c6) { src = s5; base = c5; IC = 512;  NT = 1; }
    else if (i < c7) { src = s6; base = c6; IC = 512;  NT = 1; }
    else if (i < c8) { src = s7; base = c7; IC = 128;  NT = 9; }
    else             { src = s8; base = c8; IC = 256;  NT = 9; }
    long loc = i - base;
    int ic = (int)(loc % IC);
    long r = loc / IC;
    int t = (int)(r % NT);
    long oc = r / NT;
    dst[i] = f2bf(src[(oc * IC + ic) * NT + t]);
}

// ---------------- the MFMA BT-GEMM (global_load_lds staging) ----------------
// CMODE: 0 anchors 63->65pad | 1 identity | 2 stride2@255 | 3 stride2@127
// TMODE: 1 single-tap | 4 W1(K1024) | 5 conv2 3x3 IC128 | 6 conv3 3x3 IC256
//        7 fused anchors (runtime anchor = blockIdx.x>>8)
// EMODE: 0 bias->bf16 scatter Afeat | 1 bias+relu bf16 [gn][M]
//        2 bias+sig/tanh f32 [gn][M] | 3 bias bf16 scatter h3T | 4 bias bf16 [gn][M]
template<int CMODE, int EMODE, int TMODE>
__global__ __launch_bounds__(256) void gemm_bt(
    const u16* __restrict__ A, const u16* __restrict__ B,
    const float* __restrict__ bias0, const float* __restrict__ bias1,
    const float* __restrict__ bias2, const float* __restrict__ bias3,
    void* __restrict__ Cout, int M, int N, int RSB, int Ktot,
    int OH, int OW, int obase)
{
    __shared__ u16 As[8192];   // [128 m][64 k] swizzled, 16KB
    __shared__ u16 Bs[8192];   // [128 n][64 k] swizzled
    const int tid = threadIdx.x, w = tid >> 6, l = tid & 63;
    const int wr = w >> 1, wc = w & 1;
    const int sl = l & 7, sh = l >> 3, sx = sl ^ sh;

    int n0, m0, TW = 1;
    const float* bias = bias0;
    if (TMODE == 7) {
        int anc = blockIdx.x >> 8, sub = blockIdx.x & 255;
        n0 = (sub & 31) * 128; m0 = (sub >> 5) * 128;
        Ktot = (anc == 0) ? 72 : (anc == 1) ? 8 : 24;
        TW = (anc == 0 || anc == 3) ? 3 : 1;
        A += (anc == 0) ? 0L : (anc == 1) ? 4718592L : (anc == 2) ? 5242880L : 6815744L;
        obase = (anc == 0) ? 0 : (anc == 1) ? 3721 : (anc == 2) ? 7690 : 11533;
        OH = (anc == 0 || anc == 2) ? 61 : 63;
        OW = (anc == 0 || anc == 3) ? 61 : 63;
        bias = (anc == 0) ? bias0 : (anc == 1) ? bias1 : (anc == 2) ? bias2 : bias3;
    } else {
        n0 = blockIdx.x * 128; m0 = blockIdx.y * 128;
    }
    const long RSA = (long)Ktot * 64;
    constexpr int ICL2 = (TMODE == 5) ? 1 : (TMODE == 6) ? 2 : 3;
    constexpr int KBM  = (1 << ICL2) - 1;

    int offB[4], ldsOff[4];
    long aRow[4];
#pragma unroll
    for (int j = 0; j < 4; ++j) {
        int r = w * 32 + j * 8 + sh;
        int gn = n0 + r;
        if (CMODE == 0)      { gn = min(gn, 3968);  offB[j] = (gn / 63) * 65 + (gn % 63); }
        else if (CMODE == 1) { offB[j] = min(gn, N - 1); }
        else if (CMODE == 2) { gn = min(gn, 16128); offB[j] = (gn / 127) * 510 + (gn % 127) * 2; }
        else                 { gn = min(gn, 3968);  offB[j] = (gn / 63) * 254 + (gn % 63) * 2; }
        ldsOff[j] = (w * 32 + j * 8) * 128;          // wave-uniform LDS byte base
        aRow[j] = (long)(m0 + r) * RSA * 2;
    }

    f32x4 acc[4][4];
#pragma unroll
    for (int a = 0; a < 4; ++a)
#pragma unroll
        for (int b = 0; b < 4; ++b) acc[a][b] = (f32x4){0.f, 0.f, 0.f, 0.f};

#define STAGE(kt)                                                              \
    {                                                                          \
        int t_ = (kt) >> ICL2, kb_ = (kt) & KBM;                               \
        int trow_ = 0; long tcol_ = 0;                                         \
        if (TMODE == 7)      trow_ = (t_ / TW) * 65 + (t_ % TW);               \
        else if (TMODE == 4) tcol_ = (long)t_ * 512;                           \
        else if (TMODE == 5) trow_ = (t_ / 3) * 255 + (t_ % 3);                \
        else if (TMODE == 6) trow_ = (t_ / 3) * 127 + (t_ % 3);                \
        long cbA_ = (long)(kt) * 128 + sx * 16;                                \
        long cbB_ = (tcol_ + kb_ * 64) * 2 + sx * 16;                          \
        _Pragma("unroll")                                                      \
        for (int j = 0; j < 4; ++j) {                                          \
            glds16((const char*)A + aRow[j] + cbA_, (char*)As + ldsOff[j]);    \
            glds16((const char*)B + (long)(offB[j] + trow_) * (RSB * 2) + cbB_,\
                   (char*)Bs + ldsOff[j]);                                     \
        }                                                                      \
    }

    for (int kt = 0; kt < Ktot; ++kt) {
        STAGE(kt);
        __syncthreads();          // vmcnt(0) drain -> tile ready
#pragma unroll
        for (int kk = 0; kk < 2; ++kk) {
            bf16x8 af[4], bfr[4];
#pragma unroll
            for (int f = 0; f < 4; ++f) {
                int rm = wr * 64 + f * 16 + (l & 15);
                af[f] = *(const bf16x8*)((const char*)As + rm * 128 +
                           (((kk * 4 + (l >> 4)) ^ (rm & 7)) * 16));
                int rn = wc * 64 + f * 16 + (l & 15);
                bfr[f] = *(const bf16x8*)((const char*)Bs + rn * 128 +
                           (((kk * 4 + (l >> 4)) ^ (rn & 7)) * 16));
            }
#pragma unroll
            for (int fm = 0; fm < 4; ++fm)
#pragma unroll
                for (int fn = 0; fn < 4; ++fn)
                    acc[fm][fn] = __builtin_amdgcn_mfma_f32_16x16x32_bf16(
                        af[fm], bfr[fn], acc[fm][fn], 0, 0, 0);
        }
        __syncthreads();          // all reads done before next STAGE overwrite
    }
#undef STAGE

    // epilogue
#pragma unroll
    for (int fm = 0; fm < 4; ++fm) {
        int gmb = m0 + wr * 64 + fm * 16 + (l >> 4) * 4;
#pragma unroll
        for (int fn = 0; fn < 4; ++fn) {
            int gn = n0 + wc * 64 + fn * 16 + (l & 15);
            f32x4 v = acc[fm][fn];
            if (EMODE == 0) {
                if (gn < 3969) {
                    int oy = gn / 63, ox = gn - oy * 63;
                    if (oy < OH && ox < OW) {
                        int trg = obase + oy * OW + ox;
                        float4 bv = *(const float4*)(bias + gmb);
                        u64 pk = (u64)f2bf(v.x + bv.x)
                               | ((u64)f2bf(v.y + bv.y) << 16)
                               | ((u64)f2bf(v.z + bv.z) << 32)
                               | ((u64)f2bf(v.w + bv.w) << 48);
                        *(u64*)((u16*)Cout + (long)trg * M + gmb) = pk;
                    }
                }
            } else if (EMODE == 1) {
                if (gn < N) {
                    float4 bv = *(const float4*)(bias + gmb);
                    u64 pk = (u64)f2bf(fmaxf(v.x + bv.x, 0.f))
                           | ((u64)f2bf(fmaxf(v.y + bv.y, 0.f)) << 16)
                           | ((u64)f2bf(fmaxf(v.z + bv.z, 0.f)) << 32)
                           | ((u64)f2bf(fmaxf(v.w + bv.w, 0.f)) << 48);
                    *(u64*)((u16*)Cout + (long)gn * M + gmb) = pk;
                }
            } else if (EMODE == 2) {
                if (gn < N) {
                    float4 o;
                    if (gmb < 256) {
                        float4 bv = *(const float4*)(bias0 + gmb);
                        o.x = 1.f / (1.f + expf(-(v.x + bv.x)));
                        o.y = 1.f / (1.f + expf(-(v.y + bv.y)));
                        o.z = 1.f / (1.f + expf(-(v.z + bv.z)));
                        o.w = 1.f / (1.f + expf(-(v.w + bv.w)));
                    } else {
                        float4 bv = *(const float4*)(bias1 + gmb - 256);
                        o.x = tanhf(v.x + bv.x); o.y = tanhf(v.y + bv.y);
                        o.z = tanhf(v.z + bv.z); o.w = tanhf(v.w + bv.w);
                    }
                    *(float4*)((float*)Cout + (long)gn * M + gmb) = o;
                }
            } else if (EMODE == 3) {
                if (gn < 3969) {
                    int trg = (gn / 63) * 65 + (gn % 63);
                    float4 bv = *(const float4*)(bias + gmb);
                    u64 pk = (u64)f2bf(v.x + bv.x)
                           | ((u64)f2bf(v.y + bv.y) << 16)
                           | ((u64)f2bf(v.z + bv.z) << 32)
                           | ((u64)f2bf(v.w + bv.w) << 48);
                    *(u64*)((u16*)Cout + (long)trg * M + gmb) = pk;
                }
            } else {
                if (gn < N) {
                    float4 bv = *(const float4*)(bias + gmb);
                    u64 pk = (u64)f2bf(v.x + bv.x)
                           | ((u64)f2bf(v.y + bv.y) << 16)
                           | ((u64)f2bf(v.z + bv.z) << 32)
                           | ((u64)f2bf(v.w + bv.w) << 48);
                    *(u64*)((u16*)Cout + (long)gn * M + gmb) = pk;
                }
            }
        }
    }
}

// ---------------- att[n] = sigmoid(sum_j Wa[j]*u[n][j]*v[n][j]) -------------
__global__ __launch_bounds__(256) void att_v2(
    const float* __restrict__ UVT, const float* __restrict__ Waw,
    const float* __restrict__ Wab, float* __restrict__ att, int N)
{
    int n = blockIdx.x * 256 + threadIdx.x;
    if (n >= N) return;
    const float* row = UVT + (long)n * 512;
    float s = Wab[0];
    for (int j = 0; j < 64; ++j) {
        float4 u4 = *(const float4*)(row + j * 4);
        float4 v4 = *(const float4*)(row + 256 + j * 4);
        float4 w4 = *(const float4*)(Waw + j * 4);
        s = fmaf(w4.x, u4.x * v4.x, s);
        s = fmaf(w4.y, u4.y * v4.y, s);
        s = fmaf(w4.z, u4.z * v4.z, s);
        s = fmaf(w4.w, u4.w * v4.w, s);
    }
    att[n] = 1.f / (1.f + expf(-s));
}

// ---------------- rank: chunk-parallel partial counts -----------------------
__global__ __launch_bounds__(256) void zero_int(int* __restrict__ p, int n)
{
    int i = blockIdx.x * 256 + threadIdx.x;
    if (i < n) p[i] = 0;
}

__global__ __launch_bounds__(256) void rank_partial(
    const float* __restrict__ att, int* __restrict__ rank, int N)
{
    __shared__ float sa[1024];
    int n = blockIdx.x * 256 + threadIdx.x;
    int base = blockIdx.y * 1024;
    int cnt = min(1024, N - base);
    for (int t = threadIdx.x; t < cnt; t += 256) sa[t] = att[base + t];
    __syncthreads();
    if (n >= N) return;
    float a = att[n];
    int r = 0;
    for (int t = 0; t < cnt; ++t) {
        float aj = sa[t];
        int j = base + t;
        r += (int)(aj > a) | ((int)(aj == a) & (int)(j < n));
    }
    atomicAdd(&rank[n], r);
}

__global__ __launch_bounds__(256) void cid_from_rank(
    const int* __restrict__ rank, int* __restrict__ cid, int N)
{
    int n = blockIdx.x * 256 + threadIdx.x;
    if (n < N) cid[n] = (rank[n] * 10) / N;
}

// ---------------- fc partials: register accumulators, coalesced reads -------
#define FC_NB 64
#define FC_CHUNK 241
__global__ __launch_bounds__(256) void fc_part(
    const u16* __restrict__ Hfeat, const float* __restrict__ att,
    const int* __restrict__ cid, float* __restrict__ fcp, int N)
{
    int t = threadIdx.x, b = blockIdx.x;
    float acc0[10], acc1[10];
#pragma unroll
    for (int k = 0; k < 10; ++k) { acc0[k] = 0.f; acc1[k] = 0.f; }
    int n0 = b * FC_CHUNK, n1 = min(N, n0 + FC_CHUNK);
    for (int n = n0; n < n1; ++n) {
        float a = att[n];
        int c = cid[n];
        float h0 = bf2f(Hfeat[(long)n * 512 + t]) * a;
        float h1 = bf2f(Hfeat[(long)n * 512 + t + 256]) * a;
#pragma unroll
        for (int k = 0; k < 10; ++k) {
            acc0[k] += (c == k) ? h0 : 0.f;
            acc1[k] += (c == k) ? h1 : 0.f;
        }
    }
    float* dst = fcp + (long)b * 5120;
#pragma unroll
    for (int k = 0; k < 10; ++k) {
        dst[k * 512 + t]       = acc0[k];
        dst[k * 512 + t + 256] = acc1[k];
    }
}

__global__ __launch_bounds__(256) void fc_sum(
    const float* __restrict__ fcp, float* __restrict__ fc_raw)
{
    int i = blockIdx.x * 256 + threadIdx.x;
    if (i >= 5120) return;
    float s = 0.f;
    for (int b = 0; b < FC_NB; ++b) s += fcp[(long)b * 5120 + i];
    fc_raw[i] = s;
}

// ---------------- sw/pc partials: wave shfl reduce ---------------------------
__device__ __forceinline__ void anchor_coords(int n, float& cx, float& cy,
                                              float& bw, float& bh)
{
    int kh, kw, Wa, loc;
    if (n < 3721)       { kh = 3; kw = 3; Wa = 61; loc = n; }
    else if (n < 7690)  { kh = 1; kw = 1; Wa = 63; loc = n - 3721; }
    else if (n < 11533) { kh = 3; kw = 1; Wa = 63; loc = n - 7690; }
    else                { kh = 1; kw = 3; Wa = 61; loc = n - 11533; }
    int iy = loc / Wa, ix = loc - iy * Wa;
    cx = (ix + kw * 0.5f) * (1.f / 63.f);
    cy = (iy + kh * 0.5f) * (1.f / 63.f);
    bw = kw * (1.f / 63.f);
    bh = kh * (1.f / 63.f);
}

__global__ __launch_bounds__(256) void swpc_part(
    const float* __restrict__ att, const int* __restrict__ cid,
    float* __restrict__ prt, int N)
{
    __shared__ float red[4][50];
    int t = threadIdx.x, b = blockIdx.x;
    int n = b * 256 + t;
    int l = t & 63, w = t >> 6;
    float a = 0.f, cx = 0.f, cy = 0.f, bw = 0.f, bh = 0.f;
    int c = -1;
    if (n < N) { a = att[n]; c = cid[n]; anchor_coords(n, cx, cy, bw, bh); }
#pragma unroll
    for (int k = 0; k < 10; ++k) {
        float sel = (c == k) ? a : 0.f;
        float v[5] = {sel, sel * cx, sel * cy, sel * bw, sel * bh};
#pragma unroll
        for (int d = 0; d < 5; ++d) {
            float x = v[d];
#pragma unroll
            for (int s = 1; s < 64; s <<= 1) x += __shfl_xor(x, s, 64);
            if (l == 0) red[w][k * 5 + d] = x;
        }
    }
    __syncthreads();
    if (t < 50) prt[b * 50 + t] = red[0][t] + red[1][t] + red[2][t] + red[3][t];
}

__global__ __launch_bounds__(64) void swpc_sum(
    const float* __restrict__ prt, float* __restrict__ sw,
    float* __restrict__ pcr, int NB)
{
    int j = threadIdx.x;
    if (j >= 50) return;
    float s = 0.f;
    for (int b = 0; b < NB; ++b) s += prt[b * 50 + j];
    int k = j / 5, d = j % 5;
    if (d == 0) sw[k] = s;
    else        pcr[k * 4 + (d - 1)] = s;
}

// ---------------- head ------------------------------------------------------
__global__ __launch_bounds__(512) void final_kernel(
    const float* __restrict__ fc_raw, const float* __restrict__ sw,
    const float* __restrict__ pc_raw, const float* __restrict__ cluster_w,
    const float* __restrict__ cluster_b, const float* __restrict__ cls_w,
    const float* __restrict__ cls_b, float* __restrict__ out)
{
    __shared__ float red[512];
    int t = threadIdx.x;
    float fcn[10];
#pragma unroll
    for (int k = 0; k < 10; ++k)
        fcn[k] = fc_raw[k * 512 + t] / (sw[k] + 1e-8f);
    float cw = cluster_w[t];
    float sc[10];
#pragma unroll
    for (int k = 0; k < 10; ++k) {
        red[t] = fcn[k] * cw;
        __syncthreads();
        for (int s = 256; s > 0; s >>= 1) {
            if (t < s) red[t] += red[t + s];
            __syncthreads();
        }
        sc[k] = red[0] + cluster_b[0];
        __syncthreads();
    }
    float mx = sc[0];
#pragma unroll
    for (int k = 1; k < 10; ++k) mx = fmaxf(mx, sc[k]);
    float se = 0.f;
#pragma unroll
    for (int k = 0; k < 10; ++k) { sc[k] = expf(sc[k] - mx); se += sc[k]; }
    float inv = 1.f / se;
#pragma unroll
    for (int k = 0; k < 10; ++k) sc[k] *= inv;
    float fm = 0.f;
#pragma unroll
    for (int k = 0; k < 10; ++k) fm = fmaf(sc[k], fcn[k], fm);
    float lg[10];
#pragma unroll
    for (int c = 0; c < 10; ++c) {
        red[t] = fm * cls_w[c * 512 + t];
        __syncthreads();
        for (int s = 256; s > 0; s >>= 1) {
            if (t < s) red[t] += red[t + s];
            __syncthreads();
        }
        lg[c] = red[0] + cls_b[c];
        __syncthreads();
    }
    float mx2 = lg[0];
#pragma unroll
    for (int c = 1; c < 10; ++c) mx2 = fmaxf(mx2, lg[c]);
    float se2 = 0.f;
#pragma unroll
    for (int c = 0; c < 10; ++c) { lg[c] = expf(lg[c] - mx2); se2 += lg[c]; }
    float inv2 = 1.f / se2;
    if (t < 10) out[t] = lg[t] * inv2;
    if (t >= 10 && t < 20) out[t] = sc[t - 10];
    if (t >= 20 && t < 60) {
        int i = t - 20;
        out[t] = pc_raw[i] / (sw[i >> 2] + 1e-8f);
    }
}

// ---------------------------------------------------------------------------
extern "C" void kernel_launch(void* const* d_in, const int* in_sizes, int n_in,
                              void* d_out, int out_size, void* d_ws, size_t ws_size,
                              hipStream_t stream)
{
    const float* x    = (const float*)d_in[0];
    const float* c1w  = (const float*)d_in[1];   const float* c1b = (const float*)d_in[2];
    const float* c2w  = (const float*)d_in[3];   const float* c2b = (const float*)d_in[4];
    const float* c3w  = (const float*)d_in[5];   const float* c3b = (const float*)d_in[6];
    const float* a0w  = (const float*)d_in[7];   const float* a0b = (const float*)d_in[8];
    const float* a1w  = (const float*)d_in[9];   const float* a1b = (const float*)d_in[10];
    const float* a2w  = (const float*)d_in[11];  const float* a2b = (const float*)d_in[12];
    const float* a3w  = (const float*)d_in[13];  const float* a3b = (const float*)d_in[14];
    const float* W1w  = (const float*)d_in[15];  const float* W1b = (const float*)d_in[16];
    const float* Uw   = (const float*)d_in[17];  const float* Ub  = (const float*)d_in[18];
    const float* Vw   = (const float*)d_in[19];  const float* Vb  = (const float*)d_in[20];
    const float* Waw  = (const float*)d_in[21];  const float* Wab = (const float*)d_in[22];
    const float* clw  = (const float*)d_in[23];  const float* clb = (const float*)d_in[24];
    const float* clsw = (const float*)d_in[25];  const float* clsb= (const float*)d_in[26];
    float* out = (float*)d_out;

    // ---- workspace layout (float units), lifetime overlays ---------------
    float* ws = (float*)d_ws;
    u16*   Afeat= (u16*)ws;                     // 15376*1024 u16
    u16*   h1T  = (u16*)ws;                     // 65025*128 u16 (overlay)
    u16*   Hfeat= (u16*)(ws + 7872512);         // 15376*512 u16
    float* UVT  = ws + 11808768;                // 15376*512 f32
    u16*   h2T  = (u16*)(ws + 11808768);        // 16129*256 u16 (overlay)
    u16*   h3T  = (u16*)(ws + 13873280);        // 4225*512 u16  (overlay)
    u16*   Wpk  = (u16*)(ws + 19681280);        // ALL packed weights, contiguous
    float* att  = ws + 25006080;                // 15,376
    int*   cid  = (int*)(ws + 25021456);        // 15,376
    int*   rank = (int*)(ws + 25036832);        // 15,376
    float* fcr  = ws + 25052208;                // 5,120
    float* sw   = ws + 25057328;                // 10
    float* pcr  = ws + 25057338;                // 40
    float* fcp  = ws + 25057378;                // 64*5120
    float* prt  = ws + 25385058;                // 61*50

    u16* W1pk  = Wpk + 8388608;
    u16* UVpk  = Wpk + 8912896;
    u16* Wc2pk = Wpk + 9175040;
    u16* Wc3pk = Wpk + 9469952;

    dim3 blk(256);
    const float* nul = nullptr;

    // ---- fused weight packing (one launch, 10.65M elems) -----------------
    pack_all<<<dim3(41600), blk, 0, stream>>>(a0w, a1w, a2w, a3w, W1w, Uw, Vw,
                                              c2w, c3w, Wpk);

    // ---- backbone ----------------------------------------------------------
    conv1k<<<dim3(255, 8), blk, 0, stream>>>(x, c1w, c1b, h1T);
    gemm_bt<2,4,5><<<dim3(127, 2), blk, 0, stream>>>(Wc2pk, h1T, c2b, nul, nul, nul, h2T, 256, 16129, 128, 18, 0, 0, 0);
    gemm_bt<3,3,6><<<dim3(32, 4),  blk, 0, stream>>>(Wc3pk, h2T, c3b, nul, nul, nul, h3T, 512, 3969, 256, 36, 0, 0, 0);

    // ---- fused anchor GEMMs -> Afeat[n][1024] bf16 (1024 blocks) -----------
    gemm_bt<0,0,7><<<dim3(1024), blk, 0, stream>>>(Wpk, h3T, a0b, a1b, a2b, a3b, Afeat, 1024, 3969, 512, 0, 0, 0, 0);

    // ---- W1 / UV GEMMs -----------------------------------------------------
    gemm_bt<1,1,4><<<dim3(121, 4), blk, 0, stream>>>(W1pk, Afeat, W1b, nul, nul, nul, Hfeat, 512, NTOT, 1024, 16, 0, 0, 0);
    gemm_bt<1,2,1><<<dim3(121, 4), blk, 0, stream>>>(UVpk, Hfeat, Ub, Vb, nul, nul, UVT, 512, NTOT, 512, 8, 0, 0, 0);

    // ---- attention, rank, reductions, head ---------------------------------
    att_v2<<<dim3(61), blk, 0, stream>>>(UVT, Waw, Wab, att, NTOT);
    zero_int<<<dim3(61), blk, 0, stream>>>(rank, NTOT);
    rank_partial<<<dim3(61, 16), blk, 0, stream>>>(att, rank, NTOT);
    cid_from_rank<<<dim3(61), blk, 0, stream>>>(rank, cid, NTOT);
    fc_part<<<dim3(FC_NB), blk, 0, stream>>>(Hfeat, att, cid, fcp, NTOT);
    fc_sum<<<dim3(20), blk, 0, stream>>>(fcp, fcr);
    swpc_part<<<dim3(61), blk, 0, stream>>>(att, cid, prt, NTOT);
    swpc_sum<<<dim3(1), dim3(64), 0, stream>>>(prt, sw, pcr, 61);
    final_kernel<<<dim3(1), dim3(512), 0, stream>>>(fcr, sw, pcr, clw, clb, clsw, clsb, out);
}

// Round 6
// 381.869 us; speedup vs baseline: 14.2744x; 1.2454x over previous
//
#include <hip/hip_runtime.h>
#include <math.h>

// ---------------------------------------------------------------------------
// Round 5: tail de-latency. fc_part -> 256-block wave-per-row coalesced bf16x8
// (was 64-block scalar, 105us). att path: U/V packed interleaved so the UV
// GEMM epilogue emits Wa[j]*sigmoid(u_j)*tanh(v_j) directly (UVw[n][256] f32);
// att_v3 is a coalesced wave-per-row reduction. GEMM engine unchanged.
// ---------------------------------------------------------------------------

#define NTOT 15376
typedef unsigned short u16;
typedef unsigned long long u64;
typedef __attribute__((ext_vector_type(8))) short bf16x8;
typedef __attribute__((ext_vector_type(4))) float f32x4;

static __device__ __forceinline__ u16 f2bf(float x) {
    union { float f; unsigned u; } v; v.f = x;
    unsigned r = v.u + 0x7FFF + ((v.u >> 16) & 1);
    return (u16)(r >> 16);
}
static __device__ __forceinline__ float bf2f(u16 h) {
    union { unsigned u; float f; } v; v.u = ((unsigned)h) << 16;
    return v.f;
}

// async global->LDS, 16B per lane; LDS dest = wave-uniform base + lane*16
static __device__ __forceinline__ void glds16(const void* g, void* l) {
    __builtin_amdgcn_global_load_lds(
        (const __attribute__((address_space(1))) void*)g,
        (__attribute__((address_space(3))) void*)l,
        16, 0, 0);
}

// ---------------- conv1: fp32 direct, OCB=16, bf16 transposed output --------
__global__ __launch_bounds__(256) void conv1k(
    const float* __restrict__ in, const float* __restrict__ wt,
    const float* __restrict__ bs, u16* __restrict__ h1T)
{
    int sp = blockIdx.x * 256 + threadIdx.x;
    if (sp >= 255 * 255) return;
    int oc0 = blockIdx.y * 16;
    int oy = sp / 255, ox = sp - oy * 255;
    const float* ip = in + (long)oy * 2 * 512 + ox * 2;
    float acc[16];
#pragma unroll
    for (int o = 0; o < 16; ++o) acc[o] = bs[oc0 + o];
#pragma unroll
    for (int ic = 0; ic < 3; ++ic)
#pragma unroll
        for (int ky = 0; ky < 3; ++ky)
#pragma unroll
            for (int kx = 0; kx < 3; ++kx) {
                float x = ip[ic * 262144 + ky * 512 + kx];
                const float* wp = wt + oc0 * 27 + ic * 9 + ky * 3 + kx;
#pragma unroll
                for (int o = 0; o < 16; ++o)
                    acc[o] = fmaf(x, wp[o * 27], acc[o]);
            }
    u16* dst = h1T + (long)sp * 128 + oc0;
#pragma unroll
    for (int g = 0; g < 4; ++g) {
        u64 pk = (u64)f2bf(acc[g * 4 + 0])
               | ((u64)f2bf(acc[g * 4 + 1]) << 16)
               | ((u64)f2bf(acc[g * 4 + 2]) << 32)
               | ((u64)f2bf(acc[g * 4 + 3]) << 48);
        *(u64*)(dst + g * 4) = pk;
    }
}

// ---------------- fused weight packing (U/V interleaved) --------------------
// default: dst[(oc*NT + t)*IC + ic] = src[(oc*IC+ic)*NT + t]
// UV region: row 2j = U_j, row 2j+1 = V_j  (so GEMM fragments pair u,v)
__global__ __launch_bounds__(256) void pack_all(
    const float* __restrict__ s0, const float* __restrict__ s1,
    const float* __restrict__ s2, const float* __restrict__ s3,
    const float* __restrict__ s4, const float* __restrict__ s5,
    const float* __restrict__ s6, const float* __restrict__ s7,
    const float* __restrict__ s8, u16* __restrict__ dst)
{
    long i = (long)blockIdx.x * 256 + threadIdx.x;
    if (i >= 10649600L) return;
    const long c1 = 4718592L, c2 = 5242880L, c3 = 6815744L, c4 = 8388608L,
               c5 = 8912896L, c7 = 9175040L, c8 = 9469952L;
    if (i >= c5 && i < c7) {   // interleaved U/V, IC=512
        long loc = i - c5;
        int ic = (int)(loc % 512);
        long row = loc / 512;
        const float* src = (row & 1) ? s6 : s5;
        long j = row >> 1;
        dst[i] = f2bf(src[j * 512 + ic]);
        return;
    }
    const float* src; long base; int IC, NT;
    if      (i < c1) { src = s0; base = 0;  IC = 512;  NT = 9; }
    else if (i < c2) { src = s1; base = c1; IC = 512;  NT = 1; }
    else if (i < c3) { src = s2; base = c2; IC = 512;  NT = 3; }
    else if (i < c4) { src = s3; base = c3; IC = 512;  NT = 3; }
    else if (i < c5) { src = s4; base = c4; IC = 1024; NT = 1; }
    else if (i < c8) { src = s7; base = c7; IC = 128;  NT = 9; }
    else             { src = s8; base = c8; IC = 256;  NT = 9; }
    long loc = i - base;
    int ic = (int)(loc % IC);
    long r = loc / IC;
    int t = (int)(r % NT);
    long oc = r / NT;
    dst[i] = f2bf(src[(oc * IC + ic) * NT + t]);
}

// ---------------- the MFMA BT-GEMM (global_load_lds staging) ----------------
// CMODE: 0 anchors 63->65pad | 1 identity | 2 stride2@255 | 3 stride2@127
// TMODE: 1 single-tap | 4 W1(K1024) | 5 conv2 3x3 IC128 | 6 conv3 3x3 IC256
//        7 fused anchors (runtime anchor = blockIdx.x>>8)
// EMODE: 0 bias->bf16 scatter Afeat | 1 bias+relu bf16 [gn][M]
//        2 UV head: Wa[j]*sigmoid(u)*tanh(v) -> f32 [gn][256]
//        3 bias bf16 scatter h3T | 4 bias bf16 [gn][M]
template<int CMODE, int EMODE, int TMODE>
__global__ __launch_bounds__(256) void gemm_bt(
    const u16* __restrict__ A, const u16* __restrict__ B,
    const float* __restrict__ bias0, const float* __restrict__ bias1,
    const float* __restrict__ bias2, const float* __restrict__ bias3,
    void* __restrict__ Cout, int M, int N, int RSB, int Ktot,
    int OH, int OW, int obase)
{
    __shared__ u16 As[8192];   // [128 m][64 k] swizzled, 16KB
    __shared__ u16 Bs[8192];   // [128 n][64 k] swizzled
    const int tid = threadIdx.x, w = tid >> 6, l = tid & 63;
    const int wr = w >> 1, wc = w & 1;
    const int sl = l & 7, sh = l >> 3, sx = sl ^ sh;

    int n0, m0, TW = 1;
    const float* bias = bias0;
    if (TMODE == 7) {
        int anc = blockIdx.x >> 8, sub = blockIdx.x & 255;
        n0 = (sub & 31) * 128; m0 = (sub >> 5) * 128;
        Ktot = (anc == 0) ? 72 : (anc == 1) ? 8 : 24;
        TW = (anc == 0 || anc == 3) ? 3 : 1;
        A += (anc == 0) ? 0L : (anc == 1) ? 4718592L : (anc == 2) ? 5242880L : 6815744L;
        obase = (anc == 0) ? 0 : (anc == 1) ? 3721 : (anc == 2) ? 7690 : 11533;
        OH = (anc == 0 || anc == 2) ? 61 : 63;
        OW = (anc == 0 || anc == 3) ? 61 : 63;
        bias = (anc == 0) ? bias0 : (anc == 1) ? bias1 : (anc == 2) ? bias2 : bias3;
    } else {
        n0 = blockIdx.x * 128; m0 = blockIdx.y * 128;
    }
    const long RSA = (long)Ktot * 64;
    constexpr int ICL2 = (TMODE == 5) ? 1 : (TMODE == 6) ? 2 : 3;
    constexpr int KBM  = (1 << ICL2) - 1;

    int offB[4], ldsOff[4];
    long aRow[4];
#pragma unroll
    for (int j = 0; j < 4; ++j) {
        int r = w * 32 + j * 8 + sh;
        int gn = n0 + r;
        if (CMODE == 0)      { gn = min(gn, 3968);  offB[j] = (gn / 63) * 65 + (gn % 63); }
        else if (CMODE == 1) { offB[j] = min(gn, N - 1); }
        else if (CMODE == 2) { gn = min(gn, 16128); offB[j] = (gn / 127) * 510 + (gn % 127) * 2; }
        else                 { gn = min(gn, 3968);  offB[j] = (gn / 63) * 254 + (gn % 63) * 2; }
        ldsOff[j] = (w * 32 + j * 8) * 128;          // wave-uniform LDS byte base
        aRow[j] = (long)(m0 + r) * RSA * 2;
    }

    f32x4 acc[4][4];
#pragma unroll
    for (int a = 0; a < 4; ++a)
#pragma unroll
        for (int b = 0; b < 4; ++b) acc[a][b] = (f32x4){0.f, 0.f, 0.f, 0.f};

#define STAGE(kt)                                                              \
    {                                                                          \
        int t_ = (kt) >> ICL2, kb_ = (kt) & KBM;                               \
        int trow_ = 0; long tcol_ = 0;                                         \
        if (TMODE == 7)      trow_ = (t_ / TW) * 65 + (t_ % TW);               \
        else if (TMODE == 4) tcol_ = (long)t_ * 512;                           \
        else if (TMODE == 5) trow_ = (t_ / 3) * 255 + (t_ % 3);                \
        else if (TMODE == 6) trow_ = (t_ / 3) * 127 + (t_ % 3);                \
        long cbA_ = (long)(kt) * 128 + sx * 16;                                \
        long cbB_ = (tcol_ + kb_ * 64) * 2 + sx * 16;                          \
        _Pragma("unroll")                                                      \
        for (int j = 0; j < 4; ++j) {                                          \
            glds16((const char*)A + aRow[j] + cbA_, (char*)As + ldsOff[j]);    \
            glds16((const char*)B + (long)(offB[j] + trow_) * (RSB * 2) + cbB_,\
                   (char*)Bs + ldsOff[j]);                                     \
        }                                                                      \
    }

    for (int kt = 0; kt < Ktot; ++kt) {
        STAGE(kt);
        __syncthreads();          // vmcnt(0) drain -> tile ready
#pragma unroll
        for (int kk = 0; kk < 2; ++kk) {
            bf16x8 af[4], bfr[4];
#pragma unroll
            for (int f = 0; f < 4; ++f) {
                int rm = wr * 64 + f * 16 + (l & 15);
                af[f] = *(const bf16x8*)((const char*)As + rm * 128 +
                           (((kk * 4 + (l >> 4)) ^ (rm & 7)) * 16));
                int rn = wc * 64 + f * 16 + (l & 15);
                bfr[f] = *(const bf16x8*)((const char*)Bs + rn * 128 +
                           (((kk * 4 + (l >> 4)) ^ (rn & 7)) * 16));
            }
#pragma unroll
            for (int fm = 0; fm < 4; ++fm)
#pragma unroll
                for (int fn = 0; fn < 4; ++fn)
                    acc[fm][fn] = __builtin_amdgcn_mfma_f32_16x16x32_bf16(
                        af[fm], bfr[fn], acc[fm][fn], 0, 0, 0);
        }
        __syncthreads();          // all reads done before next STAGE overwrite
    }
#undef STAGE

    // epilogue
#pragma unroll
    for (int fm = 0; fm < 4; ++fm) {
        int gmb = m0 + wr * 64 + fm * 16 + (l >> 4) * 4;
#pragma unroll
        for (int fn = 0; fn < 4; ++fn) {
            int gn = n0 + wc * 64 + fn * 16 + (l & 15);
            f32x4 v = acc[fm][fn];
            if (EMODE == 0) {
                if (gn < 3969) {
                    int oy = gn / 63, ox = gn - oy * 63;
                    if (oy < OH && ox < OW) {
                        int trg = obase + oy * OW + ox;
                        float4 bv = *(const float4*)(bias + gmb);
                        u64 pk = (u64)f2bf(v.x + bv.x)
                               | ((u64)f2bf(v.y + bv.y) << 16)
                               | ((u64)f2bf(v.z + bv.z) << 32)
                               | ((u64)f2bf(v.w + bv.w) << 48);
                        *(u64*)((u16*)Cout + (long)trg * M + gmb) = pk;
                    }
                }
            } else if (EMODE == 1) {
                if (gn < N) {
                    float4 bv = *(const float4*)(bias + gmb);
                    u64 pk = (u64)f2bf(fmaxf(v.x + bv.x, 0.f))
                           | ((u64)f2bf(fmaxf(v.y + bv.y, 0.f)) << 16)
                           | ((u64)f2bf(fmaxf(v.z + bv.z, 0.f)) << 32)
                           | ((u64)f2bf(fmaxf(v.w + bv.w, 0.f)) << 48);
                    *(u64*)((u16*)Cout + (long)gn * M + gmb) = pk;
                }
            } else if (EMODE == 2) {
                // interleaved U/V rows: v = (u_j0, v_j0, u_j0+1, v_j0+1)
                if (gn < N) {
                    int j0 = gmb >> 1;   // even
                    float u0 = 1.f / (1.f + expf(-(v.x + bias0[j0])));
                    float t0 = tanhf(v.y + bias1[j0]);
                    float u1 = 1.f / (1.f + expf(-(v.z + bias0[j0 + 1])));
                    float t1 = tanhf(v.w + bias1[j0 + 1]);
                    float2 o = { u0 * t0 * bias2[j0], u1 * t1 * bias2[j0 + 1] };
                    *(float2*)((float*)Cout + (long)gn * 256 + j0) = o;
                }
            } else if (EMODE == 3) {
                if (gn < 3969) {
                    int trg = (gn / 63) * 65 + (gn % 63);
                    float4 bv = *(const float4*)(bias + gmb);
                    u64 pk = (u64)f2bf(v.x + bv.x)
                           | ((u64)f2bf(v.y + bv.y) << 16)
                           | ((u64)f2bf(v.z + bv.z) << 32)
                           | ((u64)f2bf(v.w + bv.w) << 48);
                    *(u64*)((u16*)Cout + (long)trg * M + gmb) = pk;
                }
            } else {
                if (gn < N) {
                    float4 bv = *(const float4*)(bias + gmb);
                    u64 pk = (u64)f2bf(v.x + bv.x)
                           | ((u64)f2bf(v.y + bv.y) << 16)
                           | ((u64)f2bf(v.z + bv.z) << 32)
                           | ((u64)f2bf(v.w + bv.w) << 48);
                    *(u64*)((u16*)Cout + (long)gn * M + gmb) = pk;
                }
            }
        }
    }
}

// ---------------- att[n] = sigmoid(Wab + sum_j UVw[n][j]) -------------------
__global__ __launch_bounds__(256) void att_v3(
    const float* __restrict__ UVw, const float* __restrict__ Wab,
    float* __restrict__ att, int N)
{
    int t = threadIdx.x, l = t & 63, r = t >> 6;
    int n = blockIdx.x * 4 + r;
    if (n >= N) return;
    float4 p = *(const float4*)(UVw + (long)n * 256 + l * 4);
    float s = (p.x + p.y) + (p.z + p.w);
#pragma unroll
    for (int d = 1; d < 64; d <<= 1) s += __shfl_xor(s, d, 64);
    if (l == 0) att[n] = 1.f / (1.f + expf(-(s + Wab[0])));
}

// ---------------- rank: chunk-parallel partial counts -----------------------
__global__ __launch_bounds__(256) void zero_int(int* __restrict__ p, int n)
{
    int i = blockIdx.x * 256 + threadIdx.x;
    if (i < n) p[i] = 0;
}

__global__ __launch_bounds__(256) void rank_partial(
    const float* __restrict__ att, int* __restrict__ rank, int N)
{
    __shared__ float sa[1024];
    int n = blockIdx.x * 256 + threadIdx.x;
    int base = blockIdx.y * 1024;
    int cnt = min(1024, N - base);
    for (int t = threadIdx.x; t < cnt; t += 256) sa[t] = att[base + t];
    __syncthreads();
    if (n >= N) return;
    float a = att[n];
    int r = 0;
    for (int t = 0; t < cnt; ++t) {
        float aj = sa[t];
        int j = base + t;
        r += (int)(aj > a) | ((int)(aj == a) & (int)(j < n));
    }
    atomicAdd(&rank[n], r);
}

__global__ __launch_bounds__(256) void cid_from_rank(
    const int* __restrict__ rank, int* __restrict__ cid, int N)
{
    int n = blockIdx.x * 256 + threadIdx.x;
    if (n < N) cid[n] = (rank[n] * 10) / N;
}

// ---------------- fc partials: wave-per-row, bf16x8 coalesced ---------------
#define FC_NB 256
#define FC_ROWS 61   // 256*61 = 15616 >= 15376
__global__ __launch_bounds__(256) void fc_part(
    const u16* __restrict__ Hfeat, const float* __restrict__ att,
    const int* __restrict__ cid, float* __restrict__ fcp, int N)
{
    int t = threadIdx.x, b = blockIdx.x;
    int l = t & 63, r = t >> 6;          // lane, wave (row slot) — r wave-uniform
    float acc[10][8];
#pragma unroll
    for (int k = 0; k < 10; ++k)
#pragma unroll
        for (int e = 0; e < 8; ++e) acc[k][e] = 0.f;
    int n0 = b * FC_ROWS;
    for (int it = 0; it < 16; ++it) {
        int nl = it * 4 + r;
        int n = n0 + nl;
        if (nl >= FC_ROWS || n >= N) break;   // wave-uniform exit
        float a = att[n];
        int c = cid[n];
        bf16x8 h8 = *(const bf16x8*)(Hfeat + (long)n * 512 + l * 8);
        float hf[8];
#pragma unroll
        for (int e = 0; e < 8; ++e) hf[e] = bf2f((u16)h8[e]);
#pragma unroll
        for (int k = 0; k < 10; ++k) {
            float sel = (c == k) ? a : 0.f;
#pragma unroll
            for (int e = 0; e < 8; ++e)
                acc[k][e] = fmaf(sel, hf[e], acc[k][e]);
        }
    }
    float* dst = fcp + (long)b * 5120 + l * 8;
#pragma unroll
    for (int k = 0; k < 10; ++k)
#pragma unroll
        for (int e = 0; e < 8; ++e) dst[k * 512 + e] = acc[k][e];
}

// two-stage deterministic partial sums: fcp[256][5120] -> fcp2[16][5120] -> fcr
__global__ __launch_bounds__(256) void fc_sum1(
    const float* __restrict__ fcp, float* __restrict__ fcp2)
{
    int i = blockIdx.x * 256 + threadIdx.x;
    if (i >= 5120) return;
    int g = blockIdx.y;
    float s = 0.f;
    for (int b = g * 16; b < g * 16 + 16; ++b) s += fcp[(long)b * 5120 + i];
    fcp2[(long)g * 5120 + i] = s;
}

__global__ __launch_bounds__(256) void fc_sum2(
    const float* __restrict__ fcp2, float* __restrict__ fc_raw)
{
    int i = blockIdx.x * 256 + threadIdx.x;
    if (i >= 5120) return;
    float s = 0.f;
    for (int g = 0; g < 16; ++g) s += fcp2[(long)g * 5120 + i];
    fc_raw[i] = s;
}

// ---------------- sw/pc partials: wave shfl reduce ---------------------------
__device__ __forceinline__ void anchor_coords(int n, float& cx, float& cy,
                                              float& bw, float& bh)
{
    int kh, kw, Wa, loc;
    if (n < 3721)       { kh = 3; kw = 3; Wa = 61; loc = n; }
    else if (n < 7690)  { kh = 1; kw = 1; Wa = 63; loc = n - 3721; }
    else if (n < 11533) { kh = 3; kw = 1; Wa = 63; loc = n - 7690; }
    else                { kh = 1; kw = 3; Wa = 61; loc = n - 11533; }
    int iy = loc / Wa, ix = loc - iy * Wa;
    cx = (ix + kw * 0.5f) * (1.f / 63.f);
    cy = (iy + kh * 0.5f) * (1.f / 63.f);
    bw = kw * (1.f / 63.f);
    bh = kh * (1.f / 63.f);
}

__global__ __launch_bounds__(256) void swpc_part(
    const float* __restrict__ att, const int* __restrict__ cid,
    float* __restrict__ prt, int N)
{
    __shared__ float red[4][50];
    int t = threadIdx.x, b = blockIdx.x;
    int n = b * 256 + t;
    int l = t & 63, w = t >> 6;
    float a = 0.f, cx = 0.f, cy = 0.f, bw = 0.f, bh = 0.f;
    int c = -1;
    if (n < N) { a = att[n]; c = cid[n]; anchor_coords(n, cx, cy, bw, bh); }
#pragma unroll
    for (int k = 0; k < 10; ++k) {
        float sel = (c == k) ? a : 0.f;
        float v[5] = {sel, sel * cx, sel * cy, sel * bw, sel * bh};
#pragma unroll
        for (int d = 0; d < 5; ++d) {
            float x = v[d];
#pragma unroll
            for (int s = 1; s < 64; s <<= 1) x += __shfl_xor(x, s, 64);
            if (l == 0) red[w][k * 5 + d] = x;
        }
    }
    __syncthreads();
    if (t < 50) prt[b * 50 + t] = red[0][t] + red[1][t] + red[2][t] + red[3][t];
}

__global__ __launch_bounds__(64) void swpc_sum(
    const float* __restrict__ prt, float* __restrict__ sw,
    float* __restrict__ pcr, int NB)
{
    int j = threadIdx.x;
    if (j >= 50) return;
    float s = 0.f;
    for (int b = 0; b < NB; ++b) s += prt[b * 50 + j];
    int k = j / 5, d = j % 5;
    if (d == 0) sw[k] = s;
    else        pcr[k * 4 + (d - 1)] = s;
}

// ---------------- head ------------------------------------------------------
__global__ __launch_bounds__(512) void final_kernel(
    const float* __restrict__ fc_raw, const float* __restrict__ sw,
    const float* __restrict__ pc_raw, const float* __restrict__ cluster_w,
    const float* __restrict__ cluster_b, const float* __restrict__ cls_w,
    const float* __restrict__ cls_b, float* __restrict__ out)
{
    __shared__ float red[512];
    int t = threadIdx.x;
    float fcn[10];
#pragma unroll
    for (int k = 0; k < 10; ++k)
        fcn[k] = fc_raw[k * 512 + t] / (sw[k] + 1e-8f);
    float cw = cluster_w[t];
    float sc[10];
#pragma unroll
    for (int k = 0; k < 10; ++k) {
        red[t] = fcn[k] * cw;
        __syncthreads();
        for (int s = 256; s > 0; s >>= 1) {
            if (t < s) red[t] += red[t + s];
            __syncthreads();
        }
        sc[k] = red[0] + cluster_b[0];
        __syncthreads();
    }
    float mx = sc[0];
#pragma unroll
    for (int k = 1; k < 10; ++k) mx = fmaxf(mx, sc[k]);
    float se = 0.f;
#pragma unroll
    for (int k = 0; k < 10; ++k) { sc[k] = expf(sc[k] - mx); se += sc[k]; }
    float inv = 1.f / se;
#pragma unroll
    for (int k = 0; k < 10; ++k) sc[k] *= inv;
    float fm = 0.f;
#pragma unroll
    for (int k = 0; k < 10; ++k) fm = fmaf(sc[k], fcn[k], fm);
    float lg[10];
#pragma unroll
    for (int c = 0; c < 10; ++c) {
        red[t] = fm * cls_w[c * 512 + t];
        __syncthreads();
        for (int s = 256; s > 0; s >>= 1) {
            if (t < s) red[t] += red[t + s];
            __syncthreads();
        }
        lg[c] = red[0] + cls_b[c];
        __syncthreads();
    }
    float mx2 = lg[0];
#pragma unroll
    for (int c = 1; c < 10; ++c) mx2 = fmaxf(mx2, lg[c]);
    float se2 = 0.f;
#pragma unroll
    for (int c = 0; c < 10; ++c) { lg[c] = expf(lg[c] - mx2); se2 += lg[c]; }
    float inv2 = 1.f / se2;
    if (t < 10) out[t] = lg[t] * inv2;
    if (t >= 10 && t < 20) out[t] = sc[t - 10];
    if (t >= 20 && t < 60) {
        int i = t - 20;
        out[t] = pc_raw[i] / (sw[i >> 2] + 1e-8f);
    }
}

// ---------------------------------------------------------------------------
extern "C" void kernel_launch(void* const* d_in, const int* in_sizes, int n_in,
                              void* d_out, int out_size, void* d_ws, size_t ws_size,
                              hipStream_t stream)
{
    const float* x    = (const float*)d_in[0];
    const float* c1w  = (const float*)d_in[1];   const float* c1b = (const float*)d_in[2];
    const float* c2w  = (const float*)d_in[3];   const float* c2b = (const float*)d_in[4];
    const float* c3w  = (const float*)d_in[5];   const float* c3b = (const float*)d_in[6];
    const float* a0w  = (const float*)d_in[7];   const float* a0b = (const float*)d_in[8];
    const float* a1w  = (const float*)d_in[9];   const float* a1b = (const float*)d_in[10];
    const float* a2w  = (const float*)d_in[11];  const float* a2b = (const float*)d_in[12];
    const float* a3w  = (const float*)d_in[13];  const float* a3b = (const float*)d_in[14];
    const float* W1w  = (const float*)d_in[15];  const float* W1b = (const float*)d_in[16];
    const float* Uw   = (const float*)d_in[17];  const float* Ub  = (const float*)d_in[18];
    const float* Vw   = (const float*)d_in[19];  const float* Vb  = (const float*)d_in[20];
    const float* Waw  = (const float*)d_in[21];  const float* Wab = (const float*)d_in[22];
    const float* clw  = (const float*)d_in[23];  const float* clb = (const float*)d_in[24];
    const float* clsw = (const float*)d_in[25];  const float* clsb= (const float*)d_in[26];
    float* out = (float*)d_out;

    // ---- workspace layout (float units), lifetime overlays ---------------
    float* ws = (float*)d_ws;
    u16*   Afeat= (u16*)ws;                     // 15376*1024 u16
    u16*   h1T  = (u16*)ws;                     // 65025*128 u16 (overlay)
    u16*   Hfeat= (u16*)(ws + 7872512);         // 15376*512 u16
    float* UVw  = ws + 11808768;                // 15376*256 f32 (overlays h2T/h3T)
    u16*   h2T  = (u16*)(ws + 11808768);        // 16129*256 u16 (overlay, dead b4 UVw)
    u16*   h3T  = (u16*)(ws + 13873280);        // 4225*512 u16  (overlay, dead b4 UVw)
    u16*   Wpk  = (u16*)(ws + 19681280);        // ALL packed weights, contiguous
    float* att  = ws + 25006080;                // 15,376
    int*   cid  = (int*)(ws + 25021456);        // 15,376
    int*   rank = (int*)(ws + 25036832);        // 15,376
    float* fcr  = ws + 25052208;                // 5,120
    float* sw   = ws + 25057328;                // 10
    float* pcr  = ws + 25057338;                // 40
    float* fcp  = ws + 25057378;                // 256*5120 = 1,310,720
    float* fcp2 = ws + 26368098;                // 16*5120  = 81,920
    float* prt  = ws + 26450018;                // 61*50
    // total ~26.45M floats ~= 105.8 MB

    u16* W1pk  = Wpk + 8388608;
    u16* UVpk  = Wpk + 8912896;   // interleaved U/V, 512 rows x 512
    u16* Wc2pk = Wpk + 9175040;
    u16* Wc3pk = Wpk + 9469952;

    dim3 blk(256);
    const float* nul = nullptr;

    // ---- fused weight packing (one launch, 10.65M elems) -----------------
    pack_all<<<dim3(41600), blk, 0, stream>>>(a0w, a1w, a2w, a3w, W1w, Uw, Vw,
                                              c2w, c3w, Wpk);

    // ---- backbone ----------------------------------------------------------
    conv1k<<<dim3(255, 8), blk, 0, stream>>>(x, c1w, c1b, h1T);
    gemm_bt<2,4,5><<<dim3(127, 2), blk, 0, stream>>>(Wc2pk, h1T, c2b, nul, nul, nul, h2T, 256, 16129, 128, 18, 0, 0, 0);
    gemm_bt<3,3,6><<<dim3(32, 4),  blk, 0, stream>>>(Wc3pk, h2T, c3b, nul, nul, nul, h3T, 512, 3969, 256, 36, 0, 0, 0);

    // ---- fused anchor GEMMs -> Afeat[n][1024] bf16 (1024 blocks) -----------
    gemm_bt<0,0,7><<<dim3(1024), blk, 0, stream>>>(Wpk, h3T, a0b, a1b, a2b, a3b, Afeat, 1024, 3969, 512, 0, 0, 0, 0);

    // ---- W1 GEMM -----------------------------------------------------------
    gemm_bt<1,1,4><<<dim3(121, 4), blk, 0, stream>>>(W1pk, Afeat, W1b, nul, nul, nul, Hfeat, 512, NTOT, 1024, 16, 0, 0, 0);

    // ---- UV GEMM: UVw[n][256] = Wa[j]*sigmoid(u_j)*tanh(v_j), f32 ----------
    gemm_bt<1,2,1><<<dim3(121, 4), blk, 0, stream>>>(UVpk, Hfeat, Ub, Vb, Waw, nul, UVw, 512, NTOT, 512, 8, 0, 0, 0);

    // ---- attention, rank, reductions, head ---------------------------------
    att_v3<<<dim3(3844), blk, 0, stream>>>(UVw, Wab, att, NTOT);
    zero_int<<<dim3(61), blk, 0, stream>>>(rank, NTOT);
    rank_partial<<<dim3(61, 16), blk, 0, stream>>>(att, rank, NTOT);
    cid_from_rank<<<dim3(61), blk, 0, stream>>>(rank, cid, NTOT);
    fc_part<<<dim3(FC_NB), blk, 0, stream>>>(Hfeat, att, cid, fcp, NTOT);
    fc_sum1<<<dim3(20, 16), blk, 0, stream>>>(fcp, fcp2);
    fc_sum2<<<dim3(20), blk, 0, stream>>>(fcp2, fcr);
    swpc_part<<<dim3(61), blk, 0, stream>>>(att, cid, prt, NTOT);
    swpc_sum<<<dim3(1), dim3(64), 0, stream>>>(prt, sw, pcr, 61);
    final_kernel<<<dim3(1), dim3(512), 0, stream>>>(fcr, sw, pcr, clw, clb, clsw, clsb, out);
}

// Round 7
// 380.163 us; speedup vs baseline: 14.3385x; 1.0045x over previous
//
#include <hip/hip_runtime.h>
#include <math.h>

// ---------------------------------------------------------------------------
// Round 6: GEMM tile 128x128 -> 64m x 128n (2x blocks everywhere; fixes a0
// anchor tail at 1 block/CU and conv3 at 0.5 block/CU). acc[2][4], LDS 24KB.
// Tail: zero folded into att_v3, cid computed inline from rank, fc_sum single.
// ---------------------------------------------------------------------------

#define NTOT 15376
typedef unsigned short u16;
typedef unsigned long long u64;
typedef __attribute__((ext_vector_type(8))) short bf16x8;
typedef __attribute__((ext_vector_type(4))) float f32x4;

static __device__ __forceinline__ u16 f2bf(float x) {
    union { float f; unsigned u; } v; v.f = x;
    unsigned r = v.u + 0x7FFF + ((v.u >> 16) & 1);
    return (u16)(r >> 16);
}
static __device__ __forceinline__ float bf2f(u16 h) {
    union { unsigned u; float f; } v; v.u = ((unsigned)h) << 16;
    return v.f;
}

// async global->LDS, 16B per lane; LDS dest = wave-uniform base + lane*16
static __device__ __forceinline__ void glds16(const void* g, void* l) {
    __builtin_amdgcn_global_load_lds(
        (const __attribute__((address_space(1))) void*)g,
        (__attribute__((address_space(3))) void*)l,
        16, 0, 0);
}

// ---------------- conv1: fp32 direct, OCB=16, bf16 transposed output --------
__global__ __launch_bounds__(256) void conv1k(
    const float* __restrict__ in, const float* __restrict__ wt,
    const float* __restrict__ bs, u16* __restrict__ h1T)
{
    int sp = blockIdx.x * 256 + threadIdx.x;
    if (sp >= 255 * 255) return;
    int oc0 = blockIdx.y * 16;
    int oy = sp / 255, ox = sp - oy * 255;
    const float* ip = in + (long)oy * 2 * 512 + ox * 2;
    float acc[16];
#pragma unroll
    for (int o = 0; o < 16; ++o) acc[o] = bs[oc0 + o];
#pragma unroll
    for (int ic = 0; ic < 3; ++ic)
#pragma unroll
        for (int ky = 0; ky < 3; ++ky)
#pragma unroll
            for (int kx = 0; kx < 3; ++kx) {
                float x = ip[ic * 262144 + ky * 512 + kx];
                const float* wp = wt + oc0 * 27 + ic * 9 + ky * 3 + kx;
#pragma unroll
                for (int o = 0; o < 16; ++o)
                    acc[o] = fmaf(x, wp[o * 27], acc[o]);
            }
    u16* dst = h1T + (long)sp * 128 + oc0;
#pragma unroll
    for (int g = 0; g < 4; ++g) {
        u64 pk = (u64)f2bf(acc[g * 4 + 0])
               | ((u64)f2bf(acc[g * 4 + 1]) << 16)
               | ((u64)f2bf(acc[g * 4 + 2]) << 32)
               | ((u64)f2bf(acc[g * 4 + 3]) << 48);
        *(u64*)(dst + g * 4) = pk;
    }
}

// ---------------- fused weight packing (U/V interleaved) --------------------
__global__ __launch_bounds__(256) void pack_all(
    const float* __restrict__ s0, const float* __restrict__ s1,
    const float* __restrict__ s2, const float* __restrict__ s3,
    const float* __restrict__ s4, const float* __restrict__ s5,
    const float* __restrict__ s6, const float* __restrict__ s7,
    const float* __restrict__ s8, u16* __restrict__ dst)
{
    long i = (long)blockIdx.x * 256 + threadIdx.x;
    if (i >= 10649600L) return;
    const long c1 = 4718592L, c2 = 5242880L, c3 = 6815744L, c4 = 8388608L,
               c5 = 8912896L, c7 = 9175040L, c8 = 9469952L;
    if (i >= c5 && i < c7) {   // interleaved U/V, IC=512
        long loc = i - c5;
        int ic = (int)(loc % 512);
        long row = loc / 512;
        const float* src = (row & 1) ? s6 : s5;
        long j = row >> 1;
        dst[i] = f2bf(src[j * 512 + ic]);
        return;
    }
    const float* src; long base; int IC, NT;
    if      (i < c1) { src = s0; base = 0;  IC = 512;  NT = 9; }
    else if (i < c2) { src = s1; base = c1; IC = 512;  NT = 1; }
    else if (i < c3) { src = s2; base = c2; IC = 512;  NT = 3; }
    else if (i < c4) { src = s3; base = c3; IC = 512;  NT = 3; }
    else if (i < c5) { src = s4; base = c4; IC = 1024; NT = 1; }
    else if (i < c8) { src = s7; base = c7; IC = 128;  NT = 9; }
    else             { src = s8; base = c8; IC = 256;  NT = 9; }
    long loc = i - base;
    int ic = (int)(loc % IC);
    long r = loc / IC;
    int t = (int)(r % NT);
    long oc = r / NT;
    dst[i] = f2bf(src[(oc * IC + ic) * NT + t]);
}

// ---------------- the MFMA BT-GEMM: 64m x 128n tile --------------------------
// CMODE: 0 anchors 63->65pad | 1 identity | 2 stride2@255 | 3 stride2@127
// TMODE: 1 single-tap | 4 W1(K1024) | 5 conv2 3x3 IC128 | 6 conv3 3x3 IC256
//        7 fused anchors (runtime anchor = blockIdx.x>>9)
// EMODE: 0 bias->bf16 scatter Afeat | 1 bias+relu bf16 [gn][M]
//        2 UV head: Wa[j]*sigmoid(u)*tanh(v) -> f32 [gn][256]
//        3 bias bf16 scatter h3T | 4 bias bf16 [gn][M]
template<int CMODE, int EMODE, int TMODE>
__global__ __launch_bounds__(256) void gemm_bt(
    const u16* __restrict__ A, const u16* __restrict__ B,
    const float* __restrict__ bias0, const float* __restrict__ bias1,
    const float* __restrict__ bias2, const float* __restrict__ bias3,
    void* __restrict__ Cout, int M, int N, int RSB, int Ktot,
    int OH, int OW, int obase)
{
    __shared__ u16 As[4096];   // [64 m][64 k] swizzled, 8KB
    __shared__ u16 Bs[8192];   // [128 n][64 k] swizzled, 16KB
    const int tid = threadIdx.x, w = tid >> 6, l = tid & 63;
    const int wr = w >> 1, wc = w & 1;
    const int sl = l & 7, sh = l >> 3, sx = sl ^ sh;

    int n0, m0, TW = 1;
    const float* bias = bias0;
    if (TMODE == 7) {
        int anc = blockIdx.x >> 9, sub = blockIdx.x & 511;
        n0 = (sub & 31) * 128; m0 = (sub >> 5) * 64;
        Ktot = (anc == 0) ? 72 : (anc == 1) ? 8 : 24;
        TW = (anc == 0 || anc == 3) ? 3 : 1;
        A += (anc == 0) ? 0L : (anc == 1) ? 4718592L : (anc == 2) ? 5242880L : 6815744L;
        obase = (anc == 0) ? 0 : (anc == 1) ? 3721 : (anc == 2) ? 7690 : 11533;
        OH = (anc == 0 || anc == 2) ? 61 : 63;
        OW = (anc == 0 || anc == 3) ? 61 : 63;
        bias = (anc == 0) ? bias0 : (anc == 1) ? bias1 : (anc == 2) ? bias2 : bias3;
    } else {
        n0 = blockIdx.x * 128; m0 = blockIdx.y * 64;
    }
    const long RSA = (long)Ktot * 64;
    constexpr int ICL2 = (TMODE == 5) ? 1 : (TMODE == 6) ? 2 : 3;
    constexpr int KBM  = (1 << ICL2) - 1;

    int offB[4], ldsOffB[4], ldsOffA[2];
    long aRow[2];
#pragma unroll
    for (int j = 0; j < 4; ++j) {
        int r = w * 32 + j * 8 + sh;
        int gn = n0 + r;
        if (CMODE == 0)      { gn = min(gn, 3968);  offB[j] = (gn / 63) * 65 + (gn % 63); }
        else if (CMODE == 1) { offB[j] = min(gn, N - 1); }
        else if (CMODE == 2) { gn = min(gn, 16128); offB[j] = (gn / 127) * 510 + (gn % 127) * 2; }
        else                 { gn = min(gn, 3968);  offB[j] = (gn / 63) * 254 + (gn % 63) * 2; }
        ldsOffB[j] = r * 128;
    }
#pragma unroll
    for (int j = 0; j < 2; ++j) {
        int r = w * 16 + j * 8 + sh;
        ldsOffA[j] = r * 128;
        aRow[j] = (long)(m0 + r) * RSA * 2;
    }

    f32x4 acc[2][4];
#pragma unroll
    for (int a = 0; a < 2; ++a)
#pragma unroll
        for (int b = 0; b < 4; ++b) acc[a][b] = (f32x4){0.f, 0.f, 0.f, 0.f};

#define STAGE(kt)                                                              \
    {                                                                          \
        int t_ = (kt) >> ICL2, kb_ = (kt) & KBM;                               \
        int trow_ = 0; long tcol_ = 0;                                         \
        if (TMODE == 7)      trow_ = (t_ / TW) * 65 + (t_ % TW);               \
        else if (TMODE == 4) tcol_ = (long)t_ * 512;                           \
        else if (TMODE == 5) trow_ = (t_ / 3) * 255 + (t_ % 3);                \
        else if (TMODE == 6) trow_ = (t_ / 3) * 127 + (t_ % 3);                \
        long cbA_ = (long)(kt) * 128 + sx * 16;                                \
        long cbB_ = (tcol_ + kb_ * 64) * 2 + sx * 16;                          \
        _Pragma("unroll")                                                      \
        for (int j = 0; j < 2; ++j)                                            \
            glds16((const char*)A + aRow[j] + cbA_, (char*)As + ldsOffA[j]);   \
        _Pragma("unroll")                                                      \
        for (int j = 0; j < 4; ++j)                                            \
            glds16((const char*)B + (long)(offB[j] + trow_) * (RSB * 2) + cbB_,\
                   (char*)Bs + ldsOffB[j]);                                    \
    }

    for (int kt = 0; kt < Ktot; ++kt) {
        STAGE(kt);
        __syncthreads();          // vmcnt(0) drain -> tile ready
#pragma unroll
        for (int kk = 0; kk < 2; ++kk) {
            bf16x8 af[2], bfr[4];
#pragma unroll
            for (int f = 0; f < 2; ++f) {
                int rm = wr * 32 + f * 16 + (l & 15);
                af[f] = *(const bf16x8*)((const char*)As + rm * 128 +
                           (((kk * 4 + (l >> 4)) ^ (rm & 7)) * 16));
            }
#pragma unroll
            for (int f = 0; f < 4; ++f) {
                int rn = wc * 64 + f * 16 + (l & 15);
                bfr[f] = *(const bf16x8*)((const char*)Bs + rn * 128 +
                           (((kk * 4 + (l >> 4)) ^ (rn & 7)) * 16));
            }
#pragma unroll
            for (int fm = 0; fm < 2; ++fm)
#pragma unroll
                for (int fn = 0; fn < 4; ++fn)
                    acc[fm][fn] = __builtin_amdgcn_mfma_f32_16x16x32_bf16(
                        af[fm], bfr[fn], acc[fm][fn], 0, 0, 0);
        }
        __syncthreads();          // all reads done before next STAGE overwrite
    }
#undef STAGE

    // epilogue
#pragma unroll
    for (int fm = 0; fm < 2; ++fm) {
        int gmb = m0 + wr * 32 + fm * 16 + (l >> 4) * 4;
#pragma unroll
        for (int fn = 0; fn < 4; ++fn) {
            int gn = n0 + wc * 64 + fn * 16 + (l & 15);
            f32x4 v = acc[fm][fn];
            if (EMODE == 0) {
                if (gn < 3969) {
                    int oy = gn / 63, ox = gn - oy * 63;
                    if (oy < OH && ox < OW) {
                        int trg = obase + oy * OW + ox;
                        float4 bv = *(const float4*)(bias + gmb);
                        u64 pk = (u64)f2bf(v.x + bv.x)
                               | ((u64)f2bf(v.y + bv.y) << 16)
                               | ((u64)f2bf(v.z + bv.z) << 32)
                               | ((u64)f2bf(v.w + bv.w) << 48);
                        *(u64*)((u16*)Cout + (long)trg * M + gmb) = pk;
                    }
                }
            } else if (EMODE == 1) {
                if (gn < N) {
                    float4 bv = *(const float4*)(bias + gmb);
                    u64 pk = (u64)f2bf(fmaxf(v.x + bv.x, 0.f))
                           | ((u64)f2bf(fmaxf(v.y + bv.y, 0.f)) << 16)
                           | ((u64)f2bf(fmaxf(v.z + bv.z, 0.f)) << 32)
                           | ((u64)f2bf(fmaxf(v.w + bv.w, 0.f)) << 48);
                    *(u64*)((u16*)Cout + (long)gn * M + gmb) = pk;
                }
            } else if (EMODE == 2) {
                // interleaved U/V rows: v = (u_j0, v_j0, u_j0+1, v_j0+1)
                if (gn < N) {
                    int j0 = gmb >> 1;   // even
                    float u0 = 1.f / (1.f + expf(-(v.x + bias0[j0])));
                    float t0 = tanhf(v.y + bias1[j0]);
                    float u1 = 1.f / (1.f + expf(-(v.z + bias0[j0 + 1])));
                    float t1 = tanhf(v.w + bias1[j0 + 1]);
                    float2 o = { u0 * t0 * bias2[j0], u1 * t1 * bias2[j0 + 1] };
                    *(float2*)((float*)Cout + (long)gn * 256 + j0) = o;
                }
            } else if (EMODE == 3) {
                if (gn < 3969) {
                    int trg = (gn / 63) * 65 + (gn % 63);
                    float4 bv = *(const float4*)(bias + gmb);
                    u64 pk = (u64)f2bf(v.x + bv.x)
                           | ((u64)f2bf(v.y + bv.y) << 16)
                           | ((u64)f2bf(v.z + bv.z) << 32)
                           | ((u64)f2bf(v.w + bv.w) << 48);
                    *(u64*)((u16*)Cout + (long)trg * M + gmb) = pk;
                }
            } else {
                if (gn < N) {
                    float4 bv = *(const float4*)(bias + gmb);
                    u64 pk = (u64)f2bf(v.x + bv.x)
                           | ((u64)f2bf(v.y + bv.y) << 16)
                           | ((u64)f2bf(v.z + bv.z) << 32)
                           | ((u64)f2bf(v.w + bv.w) << 48);
                    *(u64*)((u16*)Cout + (long)gn * M + gmb) = pk;
                }
            }
        }
    }
}

// ---------------- att[n] = sigmoid(Wab + sum_j UVw[n][j]); also zeros rank --
__global__ __launch_bounds__(256) void att_v3(
    const float* __restrict__ UVw, const float* __restrict__ Wab,
    float* __restrict__ att, int* __restrict__ rank, int N)
{
    int t = threadIdx.x, l = t & 63, r = t >> 6;
    int n = blockIdx.x * 4 + r;
    if (t < 4 && blockIdx.x * 4 + t < N) rank[blockIdx.x * 4 + t] = 0;
    if (n >= N) return;
    float4 p = *(const float4*)(UVw + (long)n * 256 + l * 4);
    float s = (p.x + p.y) + (p.z + p.w);
#pragma unroll
    for (int d = 1; d < 64; d <<= 1) s += __shfl_xor(s, d, 64);
    if (l == 0) att[n] = 1.f / (1.f + expf(-(s + Wab[0])));
}

// ---------------- rank: chunk-parallel partial counts -----------------------
__global__ __launch_bounds__(256) void rank_partial(
    const float* __restrict__ att, int* __restrict__ rank, int N)
{
    __shared__ float sa[1024];
    int n = blockIdx.x * 256 + threadIdx.x;
    int base = blockIdx.y * 1024;
    int cnt = min(1024, N - base);
    for (int t = threadIdx.x; t < cnt; t += 256) sa[t] = att[base + t];
    __syncthreads();
    if (n >= N) return;
    float a = att[n];
    int r = 0;
    for (int t = 0; t < cnt; ++t) {
        float aj = sa[t];
        int j = base + t;
        r += (int)(aj > a) | ((int)(aj == a) & (int)(j < n));
    }
    atomicAdd(&rank[n], r);
}

// ---------------- fc partials: wave-per-row, bf16x8 coalesced ---------------
#define FC_NB 256
#define FC_ROWS 61   // 256*61 = 15616 >= 15376
__global__ __launch_bounds__(256) void fc_part(
    const u16* __restrict__ Hfeat, const float* __restrict__ att,
    const int* __restrict__ rank, float* __restrict__ fcp, int N)
{
    int t = threadIdx.x, b = blockIdx.x;
    int l = t & 63, r = t >> 6;
    float acc[10][8];
#pragma unroll
    for (int k = 0; k < 10; ++k)
#pragma unroll
        for (int e = 0; e < 8; ++e) acc[k][e] = 0.f;
    int n0 = b * FC_ROWS;
    for (int it = 0; it < 16; ++it) {
        int nl = it * 4 + r;
        int n = n0 + nl;
        if (nl >= FC_ROWS || n >= N) break;   // wave-uniform exit
        float a = att[n];
        int c = (rank[n] * 10) / N;
        bf16x8 h8 = *(const bf16x8*)(Hfeat + (long)n * 512 + l * 8);
        float hf[8];
#pragma unroll
        for (int e = 0; e < 8; ++e) hf[e] = bf2f((u16)h8[e]);
#pragma unroll
        for (int k = 0; k < 10; ++k) {
            float sel = (c == k) ? a : 0.f;
#pragma unroll
            for (int e = 0; e < 8; ++e)
                acc[k][e] = fmaf(sel, hf[e], acc[k][e]);
        }
    }
    float* dst = fcp + (long)b * 5120 + l * 8;
#pragma unroll
    for (int k = 0; k < 10; ++k)
#pragma unroll
        for (int e = 0; e < 8; ++e) dst[k * 512 + e] = acc[k][e];
}

// fc_raw[i] = sum_b fcp[b][i], fixed order (deterministic, coalesced)
__global__ __launch_bounds__(256) void fc_sum(
    const float* __restrict__ fcp, float* __restrict__ fc_raw)
{
    int i = blockIdx.x * 256 + threadIdx.x;
    if (i >= 5120) return;
    float s = 0.f;
    for (int b = 0; b < FC_NB; ++b) s += fcp[(long)b * 5120 + i];
    fc_raw[i] = s;
}

// ---------------- sw/pc partials: wave shfl reduce ---------------------------
__device__ __forceinline__ void anchor_coords(int n, float& cx, float& cy,
                                              float& bw, float& bh)
{
    int kh, kw, Wa, loc;
    if (n < 3721)       { kh = 3; kw = 3; Wa = 61; loc = n; }
    else if (n < 7690)  { kh = 1; kw = 1; Wa = 63; loc = n - 3721; }
    else if (n < 11533) { kh = 3; kw = 1; Wa = 63; loc = n - 7690; }
    else                { kh = 1; kw = 3; Wa = 61; loc = n - 11533; }
    int iy = loc / Wa, ix = loc - iy * Wa;
    cx = (ix + kw * 0.5f) * (1.f / 63.f);
    cy = (iy + kh * 0.5f) * (1.f / 63.f);
    bw = kw * (1.f / 63.f);
    bh = kh * (1.f / 63.f);
}

__global__ __launch_bounds__(256) void swpc_part(
    const float* __restrict__ att, const int* __restrict__ rank,
    float* __restrict__ prt, int N)
{
    __shared__ float red[4][50];
    int t = threadIdx.x, b = blockIdx.x;
    int n = b * 256 + t;
    int l = t & 63, w = t >> 6;
    float a = 0.f, cx = 0.f, cy = 0.f, bw = 0.f, bh = 0.f;
    int c = -1;
    if (n < N) {
        a = att[n]; c = (rank[n] * 10) / N;
        anchor_coords(n, cx, cy, bw, bh);
    }
#pragma unroll
    for (int k = 0; k < 10; ++k) {
        float sel = (c == k) ? a : 0.f;
        float v[5] = {sel, sel * cx, sel * cy, sel * bw, sel * bh};
#pragma unroll
        for (int d = 0; d < 5; ++d) {
            float x = v[d];
#pragma unroll
            for (int s = 1; s < 64; s <<= 1) x += __shfl_xor(x, s, 64);
            if (l == 0) red[w][k * 5 + d] = x;
        }
    }
    __syncthreads();
    if (t < 50) prt[b * 50 + t] = red[0][t] + red[1][t] + red[2][t] + red[3][t];
}

__global__ __launch_bounds__(64) void swpc_sum(
    const float* __restrict__ prt, float* __restrict__ sw,
    float* __restrict__ pcr, int NB)
{
    int j = threadIdx.x;
    if (j >= 50) return;
    float s = 0.f;
    for (int b = 0; b < NB; ++b) s += prt[b * 50 + j];
    int k = j / 5, d = j % 5;
    if (d == 0) sw[k] = s;
    else        pcr[k * 4 + (d - 1)] = s;
}

// ---------------- head ------------------------------------------------------
__global__ __launch_bounds__(512) void final_kernel(
    const float* __restrict__ fc_raw, const float* __restrict__ sw,
    const float* __restrict__ pc_raw, const float* __restrict__ cluster_w,
    const float* __restrict__ cluster_b, const float* __restrict__ cls_w,
    const float* __restrict__ cls_b, float* __restrict__ out)
{
    __shared__ float red[512];
    int t = threadIdx.x;
    float fcn[10];
#pragma unroll
    for (int k = 0; k < 10; ++k)
        fcn[k] = fc_raw[k * 512 + t] / (sw[k] + 1e-8f);
    float cw = cluster_w[t];
    float sc[10];
#pragma unroll
    for (int k = 0; k < 10; ++k) {
        red[t] = fcn[k] * cw;
        __syncthreads();
        for (int s = 256; s > 0; s >>= 1) {
            if (t < s) red[t] += red[t + s];
            __syncthreads();
        }
        sc[k] = red[0] + cluster_b[0];
        __syncthreads();
    }
    float mx = sc[0];
#pragma unroll
    for (int k = 1; k < 10; ++k) mx = fmaxf(mx, sc[k]);
    float se = 0.f;
#pragma unroll
    for (int k = 0; k < 10; ++k) { sc[k] = expf(sc[k] - mx); se += sc[k]; }
    float inv = 1.f / se;
#pragma unroll
    for (int k = 0; k < 10; ++k) sc[k] *= inv;
    float fm = 0.f;
#pragma unroll
    for (int k = 0; k < 10; ++k) fm = fmaf(sc[k], fcn[k], fm);
    float lg[10];
#pragma unroll
    for (int c = 0; c < 10; ++c) {
        red[t] = fm * cls_w[c * 512 + t];
        __syncthreads();
        for (int s = 256; s > 0; s >>= 1) {
            if (t < s) red[t] += red[t + s];
            __syncthreads();
        }
        lg[c] = red[0] + cls_b[c];
        __syncthreads();
    }
    float mx2 = lg[0];
#pragma unroll
    for (int c = 1; c < 10; ++c) mx2 = fmaxf(mx2, lg[c]);
    float se2 = 0.f;
#pragma unroll
    for (int c = 0; c < 10; ++c) { lg[c] = expf(lg[c] - mx2); se2 += lg[c]; }
    float inv2 = 1.f / se2;
    if (t < 10) out[t] = lg[t] * inv2;
    if (t >= 10 && t < 20) out[t] = sc[t - 10];
    if (t >= 20 && t < 60) {
        int i = t - 20;
        out[t] = pc_raw[i] / (sw[i >> 2] + 1e-8f);
    }
}

// ---------------------------------------------------------------------------
extern "C" void kernel_launch(void* const* d_in, const int* in_sizes, int n_in,
                              void* d_out, int out_size, void* d_ws, size_t ws_size,
                              hipStream_t stream)
{
    const float* x    = (const float*)d_in[0];
    const float* c1w  = (const float*)d_in[1];   const float* c1b = (const float*)d_in[2];
    const float* c2w  = (const float*)d_in[3];   const float* c2b = (const float*)d_in[4];
    const float* c3w  = (const float*)d_in[5];   const float* c3b = (const float*)d_in[6];
    const float* a0w  = (const float*)d_in[7];   const float* a0b = (const float*)d_in[8];
    const float* a1w  = (const float*)d_in[9];   const float* a1b = (const float*)d_in[10];
    const float* a2w  = (const float*)d_in[11];  const float* a2b = (const float*)d_in[12];
    const float* a3w  = (const float*)d_in[13];  const float* a3b = (const float*)d_in[14];
    const float* W1w  = (const float*)d_in[15];  const float* W1b = (const float*)d_in[16];
    const float* Uw   = (const float*)d_in[17];  const float* Ub  = (const float*)d_in[18];
    const float* Vw   = (const float*)d_in[19];  const float* Vb  = (const float*)d_in[20];
    const float* Waw  = (const float*)d_in[21];  const float* Wab = (const float*)d_in[22];
    const float* clw  = (const float*)d_in[23];  const float* clb = (const float*)d_in[24];
    const float* clsw = (const float*)d_in[25];  const float* clsb= (const float*)d_in[26];
    float* out = (float*)d_out;

    // ---- workspace layout (float units), lifetime overlays ---------------
    float* ws = (float*)d_ws;
    u16*   Afeat= (u16*)ws;                     // 15376*1024 u16
    u16*   h1T  = (u16*)ws;                     // 65025*128 u16 (overlay)
    u16*   Hfeat= (u16*)(ws + 7872512);         // 15376*512 u16
    float* UVw  = ws + 11808768;                // 15376*256 f32 (overlays h2T/h3T)
    u16*   h2T  = (u16*)(ws + 11808768);        // 16129*256 u16 (overlay, dead b4 UVw)
    u16*   h3T  = (u16*)(ws + 13873280);        // 4225*512 u16  (overlay, dead b4 UVw)
    u16*   Wpk  = (u16*)(ws + 19681280);        // ALL packed weights, contiguous
    float* att  = ws + 25006080;                // 15,376
    int*   rank = (int*)(ws + 25021456);        // 15,376
    float* fcr  = ws + 25036832;                // 5,120
    float* sw   = ws + 25041952;                // 10
    float* pcr  = ws + 25041962;                // 40
    float* fcp  = ws + 25042002;                // 256*5120 = 1,310,720
    float* prt  = ws + 26352722;                // 61*50
    // total ~26.36M floats ~= 105.4 MB

    u16* W1pk  = Wpk + 8388608;
    u16* UVpk  = Wpk + 8912896;   // interleaved U/V, 512 rows x 512
    u16* Wc2pk = Wpk + 9175040;
    u16* Wc3pk = Wpk + 9469952;

    dim3 blk(256);
    const float* nul = nullptr;

    // ---- fused weight packing (one launch, 10.65M elems) -----------------
    pack_all<<<dim3(41600), blk, 0, stream>>>(a0w, a1w, a2w, a3w, W1w, Uw, Vw,
                                              c2w, c3w, Wpk);

    // ---- backbone ----------------------------------------------------------
    conv1k<<<dim3(255, 8), blk, 0, stream>>>(x, c1w, c1b, h1T);
    gemm_bt<2,4,5><<<dim3(127, 4), blk, 0, stream>>>(Wc2pk, h1T, c2b, nul, nul, nul, h2T, 256, 16129, 128, 18, 0, 0, 0);
    gemm_bt<3,3,6><<<dim3(32, 8),  blk, 0, stream>>>(Wc3pk, h2T, c3b, nul, nul, nul, h3T, 512, 3969, 256, 36, 0, 0, 0);

    // ---- fused anchor GEMMs -> Afeat[n][1024] bf16 (2048 blocks) -----------
    gemm_bt<0,0,7><<<dim3(2048), blk, 0, stream>>>(Wpk, h3T, a0b, a1b, a2b, a3b, Afeat, 1024, 3969, 512, 0, 0, 0, 0);

    // ---- W1 GEMM -----------------------------------------------------------
    gemm_bt<1,1,4><<<dim3(121, 8), blk, 0, stream>>>(W1pk, Afeat, W1b, nul, nul, nul, Hfeat, 512, NTOT, 1024, 16, 0, 0, 0);

    // ---- UV GEMM: UVw[n][256] = Wa[j]*sigmoid(u_j)*tanh(v_j), f32 ----------
    gemm_bt<1,2,1><<<dim3(121, 8), blk, 0, stream>>>(UVpk, Hfeat, Ub, Vb, Waw, nul, UVw, 512, NTOT, 512, 8, 0, 0, 0);

    // ---- attention (+rank zero), rank, reductions, head --------------------
    att_v3<<<dim3(3844), blk, 0, stream>>>(UVw, Wab, att, rank, NTOT);
    rank_partial<<<dim3(61, 16), blk, 0, stream>>>(att, rank, NTOT);
    fc_part<<<dim3(FC_NB), blk, 0, stream>>>(Hfeat, att, rank, fcp, NTOT);
    fc_sum<<<dim3(20), blk, 0, stream>>>(fcp, fcr);
    swpc_part<<<dim3(61), blk, 0, stream>>>(att, rank, prt, NTOT);
    swpc_sum<<<dim3(1), dim3(64), 0, stream>>>(prt, sw, pcr, 61);
    final_kernel<<<dim3(1), dim3(512), 0, stream>>>(fcr, sw, pcr, clw, clb, clsw, clsb, out);
}